// Round 2
// baseline (945.815 us; speedup 1.0000x reference)
//
#include <hip/hip_runtime.h>

#define IN_DIM 23
#define HID 128
#define OUTD 64
#define NGR 64
#define NPART 32

// ---------------- A: int degree histogram ------------------------------------
__global__ __launch_bounds__(256) void k_hist(
    const int* __restrict__ dst, int* __restrict__ degi, int n_edges)
{
    int e = blockIdx.x * 256 + threadIdx.x;
    if (e < n_edges) atomicAdd(&degi[dst[e]], 1);
}

// ---------------- B: single-block exclusive scan -> rowstart, cursor ---------
__global__ __launch_bounds__(1024) void k_scan(
    const int* __restrict__ degi, int* __restrict__ rowstart,
    int* __restrict__ cursor, int n_nodes)
{
    __shared__ int lds[1024];
    int t = threadIdx.x;
    int chunk = (n_nodes + 1023) / 1024;
    int lo = t * chunk, hi = min(lo + chunk, n_nodes);
    int tsum = 0;
    for (int i = lo; i < hi; ++i) tsum += degi[i];
    lds[t] = tsum;
    __syncthreads();
    for (int off = 1; off < 1024; off <<= 1) {      // Hillis-Steele inclusive
        int v = (t >= off) ? lds[t - off] : 0;
        __syncthreads();
        lds[t] += v;
        __syncthreads();
    }
    int run = (t == 0) ? 0 : lds[t - 1];
    for (int i = lo; i < hi; ++i) {
        rowstart[i] = run; cursor[i] = run;
        run += degi[i];
    }
    if (t == 1023) rowstart[n_nodes] = lds[1023];
}

// ---------------- C: CSR fill (counting sort by dst) -------------------------
__global__ __launch_bounds__(256) void k_fill(
    const int* __restrict__ src, const int* __restrict__ dst,
    int* __restrict__ cursor, int* __restrict__ eidx, int n_edges)
{
    int e = blockIdx.x * 256 + threadIdx.x;
    if (e >= n_edges) return;
    int pos = atomicAdd(&cursor[dst[e]], 1);
    eidx[pos] = src[e];
}

// ---------------- D: layer-1 gather: hn = (sum feat[src] + feat[v])/(deg+1) --
// one wave per node; 2 edges per iter via lanes 0..45 = (sub, dim)
__global__ __launch_bounds__(256) void k_agg1(
    const int* __restrict__ rowstart, const int* __restrict__ eidx,
    const float* __restrict__ feat0, float* __restrict__ hn, int n_nodes)
{
    int w = (int)((blockIdx.x * 256u + threadIdx.x) >> 6);
    int lane = threadIdx.x & 63;
    if (w >= n_nodes) return;
    int v = w;
    int e0 = rowstart[v], e1 = rowstart[v + 1];
    int sub = lane / IN_DIM, d = lane - sub * IN_DIM;
    float acc = 0.f;
    if (lane < 2 * IN_DIM) {
        for (int i = e0 + sub; i < e1; i += 2) {
            int s = eidx[i];
            acc += feat0[s * IN_DIM + d];
        }
    }
    acc += __shfl(acc, lane + IN_DIM);       // lanes 0..22 pick up sub=1 partner
    if (lane < IN_DIM) {
        float degv = (float)(e1 - e0);
        hn[v * IN_DIM + lane] = (acc + feat0[v * IN_DIM + lane]) / (degv + 1.0f);
    }
}

// ---------------- E: node transform: m1 = relu(hn@W1+b1)/||.|| @ W2 ----------
__global__ __launch_bounds__(256) void k_node(
    const float* __restrict__ hn, const float* __restrict__ W1,
    const float* __restrict__ b1, const float* __restrict__ W2,
    float* __restrict__ m1, int n_nodes)
{
    __shared__ float sW1[IN_DIM * HID];
    __shared__ float sb1[HID];
    __shared__ float sW2[HID * OUTD];
    __shared__ float sh1[4][2][HID];
    __shared__ float shn[4][2][IN_DIM + 1];

    for (int i = threadIdx.x; i < IN_DIM * HID; i += 256) sW1[i] = W1[i];
    if (threadIdx.x < HID) sb1[threadIdx.x] = b1[threadIdx.x];
    for (int i = threadIdx.x; i < HID * OUTD; i += 256) sW2[i] = W2[i];

    int wave = threadIdx.x >> 6;
    int lane = threadIdx.x & 63;
    int vbase = blockIdx.x * 8 + wave * 2;

    if (lane < 2 * IN_DIM) {
        int tn = lane / IN_DIM, d = lane % IN_DIM;
        int v = vbase + tn;
        if (v < n_nodes) shn[wave][tn][d] = hn[v * IN_DIM + d];
    }
    __syncthreads();

    int k0 = lane * 2;
    float sA0 = sb1[k0], sA1 = sb1[k0 + 1];
    float sB0 = sA0, sB1 = sA1;
#pragma unroll
    for (int d = 0; d < IN_DIM; ++d) {
        float2 w = *(const float2*)&sW1[d * HID + k0];
        float a = shn[wave][0][d];
        float b = shn[wave][1][d];
        sA0 += a * w.x; sA1 += a * w.y;
        sB0 += b * w.x; sB1 += b * w.y;
    }
    sA0 = fmaxf(sA0, 0.f); sA1 = fmaxf(sA1, 0.f);
    sB0 = fmaxf(sB0, 0.f); sB1 = fmaxf(sB1, 0.f);
    float ssqA = sA0 * sA0 + sA1 * sA1;
    float ssqB = sB0 * sB0 + sB1 * sB1;
#pragma unroll
    for (int off = 32; off; off >>= 1) {
        ssqA += __shfl_xor(ssqA, off);
        ssqB += __shfl_xor(ssqB, off);
    }
    float scA = 1.0f / fmaxf(sqrtf(ssqA), 1e-12f);
    float scB = 1.0f / fmaxf(sqrtf(ssqB), 1e-12f);
    sh1[wave][0][k0] = sA0 * scA; sh1[wave][0][k0 + 1] = sA1 * scA;
    sh1[wave][1][k0] = sB0 * scB; sh1[wave][1][k0 + 1] = sB1 * scB;
    __syncthreads();

    float acc0 = 0.f, acc1 = 0.f;
#pragma unroll 8
    for (int k = 0; k < HID; ++k) {
        float w2 = sW2[k * OUTD + lane];
        acc0 += sh1[wave][0][k] * w2;
        acc1 += sh1[wave][1][k] * w2;
    }
    int v0 = vbase, v1 = vbase + 1;
    if (v0 < n_nodes) m1[v0 * OUTD + lane] = acc0;
    if (v1 < n_nodes) m1[v1 * OUTD + lane] = acc1;
}

// ---------------- F: layer-2 gather fused with per-graph mean ----------------
// wave per node, lane = out dim; coalesced 256B row reads; LDS-privatized
// graph sums flushed to NPART global partials.
__global__ __launch_bounds__(256) void k_agg2g(
    const int* __restrict__ rowstart, const int* __restrict__ eidx,
    const float* __restrict__ m1, const int* __restrict__ gids,
    float* __restrict__ gpart, float* __restrict__ gcnt, int n_nodes)
{
    __shared__ float lsum[NGR * OUTD];
    __shared__ float lcnt[NGR];
    for (int i = threadIdx.x; i < NGR * OUTD; i += 256) lsum[i] = 0.f;
    if (threadIdx.x < NGR) lcnt[threadIdx.x] = 0.f;
    __syncthreads();

    int lane = threadIdx.x & 63;
    int w = (int)((blockIdx.x * 256u + threadIdx.x) >> 6);
    int nw = (int)((gridDim.x * 256u) >> 6);
    for (int v = w; v < n_nodes; v += nw) {
        int e0 = rowstart[v], e1 = rowstart[v + 1];
        float acc = m1[(size_t)v * OUTD + lane];
        for (int i = e0; i < e1; ++i) {
            int s = eidx[i];
            acc += m1[(size_t)s * OUTD + lane];
        }
        float inv = 1.0f / ((float)(e1 - e0) + 1.0f);
        int g = gids[v];
        atomicAdd(&lsum[g * OUTD + lane], acc * inv);
        if (lane == 0) atomicAdd(&lcnt[g], 1.0f);
    }
    __syncthreads();
    float* gp = gpart + (size_t)(blockIdx.x & (NPART - 1)) * NGR * OUTD;
    for (int i = threadIdx.x; i < NGR * OUTD; i += 256) atomicAdd(&gp[i], lsum[i]);
    if (threadIdx.x < NGR) atomicAdd(&gcnt[threadIdx.x], lcnt[threadIdx.x]);
}

// ---------------- G: finalize: reduce partials, mean + b2 --------------------
__global__ __launch_bounds__(256) void k_final(
    const float* __restrict__ gpart, const float* __restrict__ gcnt,
    const float* __restrict__ b2, float* __restrict__ out)
{
    int i = blockIdx.x * 256 + threadIdx.x;
    if (i >= NGR * OUTD) return;
    int g = i >> 6, d = i & 63;
    float s = 0.f;
#pragma unroll
    for (int p = 0; p < NPART; ++p) s += gpart[(size_t)p * NGR * OUTD + i];
    float c = gcnt[g];
    out[i] = (c > 0.f) ? (s / c + b2[d]) : 0.f;
}

extern "C" void kernel_launch(void* const* d_in, const int* in_sizes, int n_in,
                              void* d_out, int out_size, void* d_ws, size_t ws_size,
                              hipStream_t stream) {
    const float* feat0 = (const float*)d_in[0];
    const float* W1    = (const float*)d_in[1];
    const float* b1    = (const float*)d_in[2];
    const float* W2    = (const float*)d_in[3];
    const float* b2    = (const float*)d_in[4];
    const int*   src   = (const int*)d_in[5];
    const int*   dst   = (const int*)d_in[6];
    const int*   gids  = (const int*)d_in[7];
    int n_edges = in_sizes[5];
    int n_nodes = in_sizes[7];

    // workspace layout (4B units): [zeroed: degi | gpart | gcnt] | rowstart |
    //                              cursor | eidx | hn | m1
    int*   degi     = (int*)d_ws;
    float* gpart    = (float*)(degi + n_nodes);
    float* gcnt     = gpart + (size_t)NPART * NGR * OUTD;
    int*   rowstart = (int*)(gcnt + NGR);
    int*   cursor   = rowstart + n_nodes + 1;
    int*   eidx     = cursor + n_nodes;
    float* hn       = (float*)(eidx + n_edges);
    float* m1       = hn + (size_t)n_nodes * IN_DIM;

    size_t zero_units = (size_t)n_nodes + (size_t)NPART * NGR * OUTD + NGR;
    hipMemsetAsync(degi, 0, zero_units * 4, stream);

    unsigned blkE = (unsigned)((n_edges + 255) / 256);
    k_hist<<<blkE, 256, 0, stream>>>(dst, degi, n_edges);

    k_scan<<<1, 1024, 0, stream>>>(degi, rowstart, cursor, n_nodes);

    k_fill<<<blkE, 256, 0, stream>>>(src, dst, cursor, eidx, n_edges);

    unsigned blkA = (unsigned)(((long long)n_nodes * 64 + 255) / 256);
    k_agg1<<<blkA, 256, 0, stream>>>(rowstart, eidx, feat0, hn, n_nodes);

    unsigned blkB = (unsigned)((n_nodes + 7) / 8);
    k_node<<<blkB, 256, 0, stream>>>(hn, W1, b1, W2, m1, n_nodes);

    k_agg2g<<<1024, 256, 0, stream>>>(rowstart, eidx, m1, gids, gpart, gcnt, n_nodes);

    k_final<<<(NGR * OUTD + 255) / 256, 256, 0, stream>>>(gpart, gcnt, b2, (float*)d_out);
}

// Round 3
// 757.803 us; speedup vs baseline: 1.2481x; 1.2481x over previous
//
#include <hip/hip_runtime.h>

#define IN_DIM 23
#define HID 128
#define OUTD 64
#define NGR 64
#define NPART 32

// ---------------- A: int degree histogram ------------------------------------
__global__ __launch_bounds__(256) void k_hist(
    const int* __restrict__ dst, int* __restrict__ degi, int n_edges)
{
    int e = blockIdx.x * 256 + threadIdx.x;
    if (e < n_edges) atomicAdd(&degi[dst[e]], 1);
}

// ---------------- B: single-block exclusive scan -> rowstart, cursor ---------
__global__ __launch_bounds__(1024) void k_scan(
    const int* __restrict__ degi, int* __restrict__ rowstart,
    int* __restrict__ cursor, int n_nodes)
{
    __shared__ int lds[1024];
    int t = threadIdx.x;
    int chunk = (n_nodes + 1023) / 1024;
    int lo = t * chunk, hi = min(lo + chunk, n_nodes);
    int tsum = 0;
    for (int i = lo; i < hi; ++i) tsum += degi[i];
    lds[t] = tsum;
    __syncthreads();
    for (int off = 1; off < 1024; off <<= 1) {      // Hillis-Steele inclusive
        int v = (t >= off) ? lds[t - off] : 0;
        __syncthreads();
        lds[t] += v;
        __syncthreads();
    }
    int run = (t == 0) ? 0 : lds[t - 1];
    for (int i = lo; i < hi; ++i) {
        rowstart[i] = run; cursor[i] = run;
        run += degi[i];
    }
    if (t == 1023) rowstart[n_nodes] = lds[1023];
}

// ---------------- C: CSR fill (counting sort by dst) -------------------------
__global__ __launch_bounds__(256) void k_fill(
    const int* __restrict__ src, const int* __restrict__ dst,
    int* __restrict__ cursor, int* __restrict__ eidx, int n_edges)
{
    int e = blockIdx.x * 256 + threadIdx.x;
    if (e >= n_edges) return;
    int pos = atomicAdd(&cursor[dst[e]], 1);
    eidx[pos] = src[e];
}

// ---------------- D: layer-1 gather: hn = (sum feat[src] + feat[v])/(deg+1) --
// wave per node. 64 indices loaded coalesced into lanes, broadcast via
// readlane; 8 edges (4 per half-wave) of independent row loads in flight.
__global__ __launch_bounds__(256) void k_agg1(
    const int* __restrict__ rowstart, const int* __restrict__ eidx,
    const float* __restrict__ feat0, float* __restrict__ hn, int n_nodes)
{
    int w = (int)((blockIdx.x * 256u + threadIdx.x) >> 6);
    int lane = threadIdx.x & 63;
    if (w >= n_nodes) return;
    int v = w;
    int e0 = rowstart[v], e1 = rowstart[v + 1];
    int nedge = e1 - e0;
    int sub = lane >> 5;          // half-wave: 0 = even edges, 1 = odd edges
    int d = lane & 31;
    bool act = d < IN_DIM;
    float acc = 0.f;
    for (int base = 0; base < nedge; base += 64) {
        int cnt = min(64, nedge - base);
        int idx = 0;
        if (lane < cnt) idx = eidx[e0 + base + lane];
        int j = 0;
        for (; j + 8 <= cnt; j += 8) {
            int a0 = __builtin_amdgcn_readlane(idx, j);
            int a1 = __builtin_amdgcn_readlane(idx, j + 1);
            int b0 = __builtin_amdgcn_readlane(idx, j + 2);
            int b1 = __builtin_amdgcn_readlane(idx, j + 3);
            int c0 = __builtin_amdgcn_readlane(idx, j + 4);
            int c1 = __builtin_amdgcn_readlane(idx, j + 5);
            int d0 = __builtin_amdgcn_readlane(idx, j + 6);
            int d1 = __builtin_amdgcn_readlane(idx, j + 7);
            int s0 = sub ? a1 : a0;
            int s1 = sub ? b1 : b0;
            int s2 = sub ? c1 : c0;
            int s3 = sub ? d1 : d0;
            if (act) {
                float f0 = feat0[(size_t)s0 * IN_DIM + d];
                float f1 = feat0[(size_t)s1 * IN_DIM + d];
                float f2 = feat0[(size_t)s2 * IN_DIM + d];
                float f3 = feat0[(size_t)s3 * IN_DIM + d];
                acc += f0 + f1 + f2 + f3;
            }
        }
        for (; j < cnt; j += 2) {
            int a0 = __builtin_amdgcn_readlane(idx, j);
            int a1 = __builtin_amdgcn_readlane(idx, min(j + 1, cnt - 1));
            int s = sub ? a1 : a0;
            if (act && (j + sub < cnt)) acc += feat0[(size_t)s * IN_DIM + d];
        }
    }
    acc += __shfl_xor(acc, 32);   // combine even/odd half-wave partials
    if (lane < IN_DIM) {
        hn[(size_t)v * IN_DIM + lane] =
            (acc + feat0[(size_t)v * IN_DIM + lane]) / ((float)nedge + 1.0f);
    }
}

// ---------------- E: node transform: m1 = relu(hn@W1+b1)/||.|| @ W2 ----------
// Persistent blocks: weights staged in LDS once; all other LDS traffic is
// intra-wave (lockstep-safe, no barriers needed).
__global__ __launch_bounds__(256) void k_node(
    const float* __restrict__ hn, const float* __restrict__ W1,
    const float* __restrict__ b1, const float* __restrict__ W2,
    float* __restrict__ m1, int n_nodes)
{
    __shared__ float sW1[IN_DIM * HID];
    __shared__ float sb1[HID];
    __shared__ float sW2[HID * OUTD];
    __shared__ float sh1[4][2][HID];
    __shared__ float shn[4][2][IN_DIM + 1];

    for (int i = threadIdx.x; i < IN_DIM * HID; i += 256) sW1[i] = W1[i];
    if (threadIdx.x < HID) sb1[threadIdx.x] = b1[threadIdx.x];
    for (int i = threadIdx.x; i < HID * OUTD; i += 256) sW2[i] = W2[i];
    __syncthreads();   // the only barrier: weight staging is cross-wave

    int wave = threadIdx.x >> 6;
    int lane = threadIdx.x & 63;

    for (int vb = blockIdx.x * 8; vb < n_nodes; vb += gridDim.x * 8) {
        int vbase = vb + wave * 2;

        if (lane < 2 * IN_DIM) {
            int tn = lane / IN_DIM, d = lane % IN_DIM;
            int v = vbase + tn;
            if (v < n_nodes) shn[wave][tn][d] = hn[(size_t)v * IN_DIM + d];
        }
        // intra-wave LDS RAW: lockstep + compiler lgkmcnt, no barrier

        int k0 = lane * 2;
        float sA0 = sb1[k0], sA1 = sb1[k0 + 1];
        float sB0 = sA0, sB1 = sA1;
#pragma unroll
        for (int d = 0; d < IN_DIM; ++d) {
            float2 wv = *(const float2*)&sW1[d * HID + k0];
            float a = shn[wave][0][d];
            float b = shn[wave][1][d];
            sA0 += a * wv.x; sA1 += a * wv.y;
            sB0 += b * wv.x; sB1 += b * wv.y;
        }
        sA0 = fmaxf(sA0, 0.f); sA1 = fmaxf(sA1, 0.f);
        sB0 = fmaxf(sB0, 0.f); sB1 = fmaxf(sB1, 0.f);
        float ssqA = sA0 * sA0 + sA1 * sA1;
        float ssqB = sB0 * sB0 + sB1 * sB1;
#pragma unroll
        for (int off = 32; off; off >>= 1) {
            ssqA += __shfl_xor(ssqA, off);
            ssqB += __shfl_xor(ssqB, off);
        }
        float scA = 1.0f / fmaxf(sqrtf(ssqA), 1e-12f);
        float scB = 1.0f / fmaxf(sqrtf(ssqB), 1e-12f);
        sh1[wave][0][k0] = sA0 * scA; sh1[wave][0][k0 + 1] = sA1 * scA;
        sh1[wave][1][k0] = sB0 * scB; sh1[wave][1][k0 + 1] = sB1 * scB;

        float acc0 = 0.f, acc1 = 0.f;
#pragma unroll 8
        for (int k = 0; k < HID; ++k) {
            float w2 = sW2[k * OUTD + lane];
            acc0 += sh1[wave][0][k] * w2;
            acc1 += sh1[wave][1][k] * w2;
        }
        int v0 = vbase, v1 = vbase + 1;
        if (v0 < n_nodes) m1[(size_t)v0 * OUTD + lane] = acc0;
        if (v1 < n_nodes) m1[(size_t)v1 * OUTD + lane] = acc1;
    }
}

// ---------------- F: layer-2 gather fused with per-graph mean ----------------
// wave per node (grid-stride), lane = out dim. Index broadcast + unroll-4
// independent 256B row gathers; LDS-privatized graph sums.
__global__ __launch_bounds__(256) void k_agg2g(
    const int* __restrict__ rowstart, const int* __restrict__ eidx,
    const float* __restrict__ m1, const int* __restrict__ gids,
    float* __restrict__ gpart, float* __restrict__ gcnt, int n_nodes)
{
    __shared__ float lsum[NGR * OUTD];
    __shared__ float lcnt[NGR];
    for (int i = threadIdx.x; i < NGR * OUTD; i += 256) lsum[i] = 0.f;
    if (threadIdx.x < NGR) lcnt[threadIdx.x] = 0.f;
    __syncthreads();

    int lane = threadIdx.x & 63;
    int w = (int)((blockIdx.x * 256u + threadIdx.x) >> 6);
    int nw = (int)((gridDim.x * 256u) >> 6);
    for (int v = w; v < n_nodes; v += nw) {
        int e0 = rowstart[v], e1 = rowstart[v + 1];
        int nedge = e1 - e0;
        float acc = m1[(size_t)v * OUTD + lane];
        for (int base = 0; base < nedge; base += 64) {
            int cnt = min(64, nedge - base);
            int idx = 0;
            if (lane < cnt) idx = eidx[e0 + base + lane];
            int j = 0;
            for (; j + 4 <= cnt; j += 4) {
                int s0 = __builtin_amdgcn_readlane(idx, j);
                int s1 = __builtin_amdgcn_readlane(idx, j + 1);
                int s2 = __builtin_amdgcn_readlane(idx, j + 2);
                int s3 = __builtin_amdgcn_readlane(idx, j + 3);
                float a0 = m1[(size_t)s0 * OUTD + lane];
                float a1 = m1[(size_t)s1 * OUTD + lane];
                float a2 = m1[(size_t)s2 * OUTD + lane];
                float a3 = m1[(size_t)s3 * OUTD + lane];
                acc += a0 + a1 + a2 + a3;
            }
            for (; j < cnt; ++j) {
                int s = __builtin_amdgcn_readlane(idx, j);
                acc += m1[(size_t)s * OUTD + lane];
            }
        }
        float inv = 1.0f / ((float)nedge + 1.0f);
        int g = gids[v];
        atomicAdd(&lsum[g * OUTD + lane], acc * inv);
        if (lane == 0) atomicAdd(&lcnt[g], 1.0f);
    }
    __syncthreads();
    float* gp = gpart + (size_t)(blockIdx.x & (NPART - 1)) * NGR * OUTD;
    for (int i = threadIdx.x; i < NGR * OUTD; i += 256) atomicAdd(&gp[i], lsum[i]);
    if (threadIdx.x < NGR) atomicAdd(&gcnt[threadIdx.x], lcnt[threadIdx.x]);
}

// ---------------- G: finalize: reduce partials, mean + b2 --------------------
__global__ __launch_bounds__(256) void k_final(
    const float* __restrict__ gpart, const float* __restrict__ gcnt,
    const float* __restrict__ b2, float* __restrict__ out)
{
    int i = blockIdx.x * 256 + threadIdx.x;
    if (i >= NGR * OUTD) return;
    int g = i >> 6, d = i & 63;
    float s = 0.f;
#pragma unroll
    for (int p = 0; p < NPART; ++p) s += gpart[(size_t)p * NGR * OUTD + i];
    float c = gcnt[g];
    out[i] = (c > 0.f) ? (s / c + b2[d]) : 0.f;
}

extern "C" void kernel_launch(void* const* d_in, const int* in_sizes, int n_in,
                              void* d_out, int out_size, void* d_ws, size_t ws_size,
                              hipStream_t stream) {
    const float* feat0 = (const float*)d_in[0];
    const float* W1    = (const float*)d_in[1];
    const float* b1    = (const float*)d_in[2];
    const float* W2    = (const float*)d_in[3];
    const float* b2    = (const float*)d_in[4];
    const int*   src   = (const int*)d_in[5];
    const int*   dst   = (const int*)d_in[6];
    const int*   gids  = (const int*)d_in[7];
    int n_edges = in_sizes[5];
    int n_nodes = in_sizes[7];

    // workspace layout (4B units): [zeroed: degi | gpart | gcnt] | rowstart |
    //                              cursor | eidx | hn | m1
    int*   degi     = (int*)d_ws;
    float* gpart    = (float*)(degi + n_nodes);
    float* gcnt     = gpart + (size_t)NPART * NGR * OUTD;
    int*   rowstart = (int*)(gcnt + NGR);
    int*   cursor   = rowstart + n_nodes + 1;
    int*   eidx     = cursor + n_nodes;
    float* hn       = (float*)(eidx + n_edges);
    float* m1       = hn + (size_t)n_nodes * IN_DIM;

    size_t zero_units = (size_t)n_nodes + (size_t)NPART * NGR * OUTD + NGR;
    hipMemsetAsync(degi, 0, zero_units * 4, stream);

    unsigned blkE = (unsigned)((n_edges + 255) / 256);
    k_hist<<<blkE, 256, 0, stream>>>(dst, degi, n_edges);

    k_scan<<<1, 1024, 0, stream>>>(degi, rowstart, cursor, n_nodes);

    k_fill<<<blkE, 256, 0, stream>>>(src, dst, cursor, eidx, n_edges);

    unsigned blkA = (unsigned)(((long long)n_nodes * 64 + 255) / 256);
    k_agg1<<<blkA, 256, 0, stream>>>(rowstart, eidx, feat0, hn, n_nodes);

    k_node<<<1024, 256, 0, stream>>>(hn, W1, b1, W2, m1, n_nodes);

    k_agg2g<<<2048, 256, 0, stream>>>(rowstart, eidx, m1, gids, gpart, gcnt, n_nodes);

    k_final<<<(NGR * OUTD + 255) / 256, 256, 0, stream>>>(gpart, gcnt, b2, (float*)d_out);
}

// Round 4
// 535.342 us; speedup vs baseline: 1.7667x; 1.4156x over previous
//
#include <hip/hip_runtime.h>

#define IN_DIM 23
#define HID 128
#define OUTD 64
#define NGR 64
#define NPART 32

// ---------------- A: int degree histogram ------------------------------------
__global__ __launch_bounds__(256) void k_hist(
    const int* __restrict__ dst, int* __restrict__ degi, int n_edges)
{
    int e = blockIdx.x * 256 + threadIdx.x;
    if (e < n_edges) atomicAdd(&degi[dst[e]], 1);
}

// ---------------- B1: per-block local exclusive scan + block totals ----------
// 4 nodes/thread via int4; shfl wave-scan; LDS cross-wave combine.
__global__ __launch_bounds__(256) void k_scan_local(
    const int* __restrict__ degi, int* __restrict__ local,
    int* __restrict__ bsum, int n_nodes)
{
    int base = blockIdx.x * 1024 + threadIdx.x * 4;
    int4 d = {0, 0, 0, 0};
    if (base + 3 < n_nodes) {
        d = *(const int4*)&degi[base];
    } else {
        if (base + 0 < n_nodes) d.x = degi[base + 0];
        if (base + 1 < n_nodes) d.y = degi[base + 1];
        if (base + 2 < n_nodes) d.z = degi[base + 2];
        if (base + 3 < n_nodes) d.w = degi[base + 3];
    }
    int tsum = d.x + d.y + d.z + d.w;
    int lane = threadIdx.x & 63;
    int wave = threadIdx.x >> 6;
    int s = tsum;                       // inclusive wave scan
#pragma unroll
    for (int off = 1; off < 64; off <<= 1) {
        int v = __shfl_up(s, off);
        if (lane >= off) s += v;
    }
    __shared__ int wtot[4];
    if (lane == 63) wtot[wave] = s;
    __syncthreads();
    int woff = 0;
#pragma unroll
    for (int i = 0; i < 4; ++i) woff += (i < wave) ? wtot[i] : 0;
    int excl = woff + s - tsum;         // exclusive prefix within block
    int l0 = excl;
    int l1 = l0 + d.x;
    int l2 = l1 + d.y;
    int l3 = l2 + d.z;
    if (base + 3 < n_nodes) {
        *(int4*)&local[base] = make_int4(l0, l1, l2, l3);
    } else {
        if (base + 0 < n_nodes) local[base + 0] = l0;
        if (base + 1 < n_nodes) local[base + 1] = l1;
        if (base + 2 < n_nodes) local[base + 2] = l2;
        if (base + 3 < n_nodes) local[base + 3] = l3;
    }
    if (threadIdx.x == 255) bsum[blockIdx.x] = excl + tsum;  // block total
}

// ---------------- B2: scan the (<=1024) block totals -------------------------
__global__ __launch_bounds__(1024) void k_scan_bsum(
    const int* __restrict__ bsum, int* __restrict__ boff,
    int* __restrict__ rowstart, int nb, int n_nodes, int n_edges)
{
    __shared__ int lds[1024];
    int t = threadIdx.x;
    lds[t] = (t < nb) ? bsum[t] : 0;
    __syncthreads();
    for (int off = 1; off < 1024; off <<= 1) {
        int v = (t >= off) ? lds[t - off] : 0;
        __syncthreads();
        lds[t] += v;
        __syncthreads();
    }
    if (t < nb) boff[t] = (t == 0) ? 0 : lds[t - 1];
    if (t == 0) rowstart[n_nodes] = n_edges;
}

// ---------------- B3: apply block offsets -> rowstart, cursor ----------------
__global__ __launch_bounds__(256) void k_scan_apply(
    const int* __restrict__ local, const int* __restrict__ boff,
    int* __restrict__ rowstart, int* __restrict__ cursor, int n_nodes)
{
    int base = blockIdx.x * 1024 + threadIdx.x * 4;
    int off = boff[blockIdx.x];
    if (base + 3 < n_nodes) {
        int4 l = *(const int4*)&local[base];
        int4 r = make_int4(l.x + off, l.y + off, l.z + off, l.w + off);
        *(int4*)&rowstart[base] = r;
        *(int4*)&cursor[base] = r;
    } else {
        for (int i = 0; i < 4; ++i) {
            if (base + i < n_nodes) {
                int r = local[base + i] + off;
                rowstart[base + i] = r;
                cursor[base + i] = r;
            }
        }
    }
}

// ---------------- C: CSR fill (counting sort by dst) -------------------------
__global__ __launch_bounds__(256) void k_fill(
    const int* __restrict__ src, const int* __restrict__ dst,
    int* __restrict__ cursor, int* __restrict__ eidx, int n_edges)
{
    int e = blockIdx.x * 256 + threadIdx.x;
    if (e >= n_edges) return;
    int pos = atomicAdd(&cursor[dst[e]], 1);
    eidx[pos] = src[e];
}

// ---------------- D: layer-1 gather: hn = (sum feat[src] + feat[v])/(deg+1) --
__global__ __launch_bounds__(256) void k_agg1(
    const int* __restrict__ rowstart, const int* __restrict__ eidx,
    const float* __restrict__ feat0, float* __restrict__ hn, int n_nodes)
{
    int w = (int)((blockIdx.x * 256u + threadIdx.x) >> 6);
    int lane = threadIdx.x & 63;
    if (w >= n_nodes) return;
    int v = w;
    int e0 = rowstart[v], e1 = rowstart[v + 1];
    int nedge = e1 - e0;
    int sub = lane >> 5;          // half-wave: 0 = even edges, 1 = odd edges
    int d = lane & 31;
    bool act = d < IN_DIM;
    float acc = 0.f;
    for (int base = 0; base < nedge; base += 64) {
        int cnt = min(64, nedge - base);
        int idx = 0;
        if (lane < cnt) idx = eidx[e0 + base + lane];
        int j = 0;
        for (; j + 8 <= cnt; j += 8) {
            int a0 = __builtin_amdgcn_readlane(idx, j);
            int a1 = __builtin_amdgcn_readlane(idx, j + 1);
            int b0 = __builtin_amdgcn_readlane(idx, j + 2);
            int b1 = __builtin_amdgcn_readlane(idx, j + 3);
            int c0 = __builtin_amdgcn_readlane(idx, j + 4);
            int c1 = __builtin_amdgcn_readlane(idx, j + 5);
            int d0 = __builtin_amdgcn_readlane(idx, j + 6);
            int d1 = __builtin_amdgcn_readlane(idx, j + 7);
            int s0 = sub ? a1 : a0;
            int s1 = sub ? b1 : b0;
            int s2 = sub ? c1 : c0;
            int s3 = sub ? d1 : d0;
            if (act) {
                float f0 = feat0[(size_t)s0 * IN_DIM + d];
                float f1 = feat0[(size_t)s1 * IN_DIM + d];
                float f2 = feat0[(size_t)s2 * IN_DIM + d];
                float f3 = feat0[(size_t)s3 * IN_DIM + d];
                acc += f0 + f1 + f2 + f3;
            }
        }
        for (; j < cnt; j += 2) {
            int a0 = __builtin_amdgcn_readlane(idx, j);
            int a1 = __builtin_amdgcn_readlane(idx, min(j + 1, cnt - 1));
            int s = sub ? a1 : a0;
            if (act && (j + sub < cnt)) acc += feat0[(size_t)s * IN_DIM + d];
        }
    }
    acc += __shfl_xor(acc, 32);   // combine even/odd half-wave partials
    if (lane < IN_DIM) {
        hn[(size_t)v * IN_DIM + lane] =
            (acc + feat0[(size_t)v * IN_DIM + lane]) / ((float)nedge + 1.0f);
    }
}

// ---------------- E: node transform: m1 = relu(hn@W1+b1)/||.|| @ W2 ----------
__global__ __launch_bounds__(256) void k_node(
    const float* __restrict__ hn, const float* __restrict__ W1,
    const float* __restrict__ b1, const float* __restrict__ W2,
    float* __restrict__ m1, int n_nodes)
{
    __shared__ float sW1[IN_DIM * HID];
    __shared__ float sb1[HID];
    __shared__ float sW2[HID * OUTD];
    __shared__ float sh1[4][2][HID];
    __shared__ float shn[4][2][IN_DIM + 1];

    for (int i = threadIdx.x; i < IN_DIM * HID; i += 256) sW1[i] = W1[i];
    if (threadIdx.x < HID) sb1[threadIdx.x] = b1[threadIdx.x];
    for (int i = threadIdx.x; i < HID * OUTD; i += 256) sW2[i] = W2[i];
    __syncthreads();   // the only barrier: weight staging is cross-wave

    int wave = threadIdx.x >> 6;
    int lane = threadIdx.x & 63;

    for (int vb = blockIdx.x * 8; vb < n_nodes; vb += gridDim.x * 8) {
        int vbase = vb + wave * 2;

        if (lane < 2 * IN_DIM) {
            int tn = lane / IN_DIM, d = lane % IN_DIM;
            int v = vbase + tn;
            if (v < n_nodes) shn[wave][tn][d] = hn[(size_t)v * IN_DIM + d];
        }
        // intra-wave LDS RAW: lockstep + compiler lgkmcnt, no barrier

        int k0 = lane * 2;
        float sA0 = sb1[k0], sA1 = sb1[k0 + 1];
        float sB0 = sA0, sB1 = sA1;
#pragma unroll
        for (int d = 0; d < IN_DIM; ++d) {
            float2 wv = *(const float2*)&sW1[d * HID + k0];
            float a = shn[wave][0][d];
            float b = shn[wave][1][d];
            sA0 += a * wv.x; sA1 += a * wv.y;
            sB0 += b * wv.x; sB1 += b * wv.y;
        }
        sA0 = fmaxf(sA0, 0.f); sA1 = fmaxf(sA1, 0.f);
        sB0 = fmaxf(sB0, 0.f); sB1 = fmaxf(sB1, 0.f);
        float ssqA = sA0 * sA0 + sA1 * sA1;
        float ssqB = sB0 * sB0 + sB1 * sB1;
#pragma unroll
        for (int off = 32; off; off >>= 1) {
            ssqA += __shfl_xor(ssqA, off);
            ssqB += __shfl_xor(ssqB, off);
        }
        float scA = 1.0f / fmaxf(sqrtf(ssqA), 1e-12f);
        float scB = 1.0f / fmaxf(sqrtf(ssqB), 1e-12f);
        sh1[wave][0][k0] = sA0 * scA; sh1[wave][0][k0 + 1] = sA1 * scA;
        sh1[wave][1][k0] = sB0 * scB; sh1[wave][1][k0 + 1] = sB1 * scB;

        float acc0 = 0.f, acc1 = 0.f;
#pragma unroll 8
        for (int k = 0; k < HID; ++k) {
            float w2 = sW2[k * OUTD + lane];
            acc0 += sh1[wave][0][k] * w2;
            acc1 += sh1[wave][1][k] * w2;
        }
        int v0 = vbase, v1 = vbase + 1;
        if (v0 < n_nodes) m1[(size_t)v0 * OUTD + lane] = acc0;
        if (v1 < n_nodes) m1[(size_t)v1 * OUTD + lane] = acc1;
    }
}

// ---------------- F: layer-2 gather fused with per-graph mean ----------------
__global__ __launch_bounds__(256) void k_agg2g(
    const int* __restrict__ rowstart, const int* __restrict__ eidx,
    const float* __restrict__ m1, const int* __restrict__ gids,
    float* __restrict__ gpart, float* __restrict__ gcnt, int n_nodes)
{
    __shared__ float lsum[NGR * OUTD];
    __shared__ float lcnt[NGR];
    for (int i = threadIdx.x; i < NGR * OUTD; i += 256) lsum[i] = 0.f;
    if (threadIdx.x < NGR) lcnt[threadIdx.x] = 0.f;
    __syncthreads();

    int lane = threadIdx.x & 63;
    int w = (int)((blockIdx.x * 256u + threadIdx.x) >> 6);
    int nw = (int)((gridDim.x * 256u) >> 6);
    for (int v = w; v < n_nodes; v += nw) {
        int e0 = rowstart[v], e1 = rowstart[v + 1];
        int nedge = e1 - e0;
        float acc = m1[(size_t)v * OUTD + lane];
        for (int base = 0; base < nedge; base += 64) {
            int cnt = min(64, nedge - base);
            int idx = 0;
            if (lane < cnt) idx = eidx[e0 + base + lane];
            int j = 0;
            for (; j + 4 <= cnt; j += 4) {
                int s0 = __builtin_amdgcn_readlane(idx, j);
                int s1 = __builtin_amdgcn_readlane(idx, j + 1);
                int s2 = __builtin_amdgcn_readlane(idx, j + 2);
                int s3 = __builtin_amdgcn_readlane(idx, j + 3);
                float a0 = m1[(size_t)s0 * OUTD + lane];
                float a1 = m1[(size_t)s1 * OUTD + lane];
                float a2 = m1[(size_t)s2 * OUTD + lane];
                float a3 = m1[(size_t)s3 * OUTD + lane];
                acc += a0 + a1 + a2 + a3;
            }
            for (; j < cnt; ++j) {
                int s = __builtin_amdgcn_readlane(idx, j);
                acc += m1[(size_t)s * OUTD + lane];
            }
        }
        float inv = 1.0f / ((float)nedge + 1.0f);
        int g = gids[v];
        atomicAdd(&lsum[g * OUTD + lane], acc * inv);
        if (lane == 0) atomicAdd(&lcnt[g], 1.0f);
    }
    __syncthreads();
    float* gp = gpart + (size_t)(blockIdx.x & (NPART - 1)) * NGR * OUTD;
    for (int i = threadIdx.x; i < NGR * OUTD; i += 256) atomicAdd(&gp[i], lsum[i]);
    if (threadIdx.x < NGR) atomicAdd(&gcnt[threadIdx.x], lcnt[threadIdx.x]);
}

// ---------------- G: finalize: reduce partials, mean + b2 --------------------
__global__ __launch_bounds__(256) void k_final(
    const float* __restrict__ gpart, const float* __restrict__ gcnt,
    const float* __restrict__ b2, float* __restrict__ out)
{
    int i = blockIdx.x * 256 + threadIdx.x;
    if (i >= NGR * OUTD) return;
    int g = i >> 6, d = i & 63;
    float s = 0.f;
#pragma unroll
    for (int p = 0; p < NPART; ++p) s += gpart[(size_t)p * NGR * OUTD + i];
    float c = gcnt[g];
    out[i] = (c > 0.f) ? (s / c + b2[d]) : 0.f;
}

extern "C" void kernel_launch(void* const* d_in, const int* in_sizes, int n_in,
                              void* d_out, int out_size, void* d_ws, size_t ws_size,
                              hipStream_t stream) {
    const float* feat0 = (const float*)d_in[0];
    const float* W1    = (const float*)d_in[1];
    const float* b1    = (const float*)d_in[2];
    const float* W2    = (const float*)d_in[3];
    const float* b2    = (const float*)d_in[4];
    const int*   src   = (const int*)d_in[5];
    const int*   dst   = (const int*)d_in[6];
    const int*   gids  = (const int*)d_in[7];
    int n_edges = in_sizes[5];
    int n_nodes = in_sizes[7];

    int nb = (n_nodes + 1023) / 1024;   // scan blocks (98 for 100K nodes)

    // workspace layout (4B units): [zeroed: degi | gpart | gcnt] | rowstart |
    //                              cursor | local | bsum | boff | eidx | hn | m1
    int*   degi     = (int*)d_ws;
    float* gpart    = (float*)(degi + n_nodes);
    float* gcnt     = gpart + (size_t)NPART * NGR * OUTD;
    int*   rowstart = (int*)(gcnt + NGR);
    int*   cursor   = rowstart + n_nodes + 1;
    int*   local    = cursor + n_nodes;
    int*   bsum     = local + n_nodes;
    int*   boff     = bsum + nb;
    int*   eidx     = boff + nb;
    float* hn       = (float*)(eidx + n_edges);
    float* m1       = hn + (size_t)n_nodes * IN_DIM;

    size_t zero_units = (size_t)n_nodes + (size_t)NPART * NGR * OUTD + NGR;
    hipMemsetAsync(degi, 0, zero_units * 4, stream);

    unsigned blkE = (unsigned)((n_edges + 255) / 256);
    k_hist<<<blkE, 256, 0, stream>>>(dst, degi, n_edges);

    k_scan_local<<<nb, 256, 0, stream>>>(degi, local, bsum, n_nodes);
    k_scan_bsum<<<1, 1024, 0, stream>>>(bsum, boff, rowstart, nb, n_nodes, n_edges);
    k_scan_apply<<<nb, 256, 0, stream>>>(local, boff, rowstart, cursor, n_nodes);

    k_fill<<<blkE, 256, 0, stream>>>(src, dst, cursor, eidx, n_edges);

    unsigned blkA = (unsigned)(((long long)n_nodes * 64 + 255) / 256);
    k_agg1<<<blkA, 256, 0, stream>>>(rowstart, eidx, feat0, hn, n_nodes);

    k_node<<<1024, 256, 0, stream>>>(hn, W1, b1, W2, m1, n_nodes);

    k_agg2g<<<2048, 256, 0, stream>>>(rowstart, eidx, m1, gids, gpart, gcnt, n_nodes);

    k_final<<<(NGR * OUTD + 255) / 256, 256, 0, stream>>>(gpart, gcnt, b2, (float*)d_out);
}

// Round 5
// 479.284 us; speedup vs baseline: 1.9734x; 1.1170x over previous
//
#include <hip/hip_runtime.h>

#define IN_DIM 23
#define HID 128
#define OUTD 64
#define NGR 64
#define NPART 32
#define FILL_GRP 8

// ---------------- A: int degree histogram ------------------------------------
__global__ __launch_bounds__(256) void k_hist(
    const int* __restrict__ dst, int* __restrict__ degi, int n_edges)
{
    int e = blockIdx.x * 256 + threadIdx.x;
    if (e < n_edges) atomicAdd(&degi[dst[e]], 1);
}

// ---------------- B1: per-block local exclusive scan + block totals ----------
__global__ __launch_bounds__(256) void k_scan_local(
    const int* __restrict__ degi, int* __restrict__ local,
    int* __restrict__ bsum, int n_nodes)
{
    int base = blockIdx.x * 1024 + threadIdx.x * 4;
    int4 d = {0, 0, 0, 0};
    if (base + 3 < n_nodes) {
        d = *(const int4*)&degi[base];
    } else {
        if (base + 0 < n_nodes) d.x = degi[base + 0];
        if (base + 1 < n_nodes) d.y = degi[base + 1];
        if (base + 2 < n_nodes) d.z = degi[base + 2];
        if (base + 3 < n_nodes) d.w = degi[base + 3];
    }
    int tsum = d.x + d.y + d.z + d.w;
    int lane = threadIdx.x & 63;
    int wave = threadIdx.x >> 6;
    int s = tsum;                       // inclusive wave scan
#pragma unroll
    for (int off = 1; off < 64; off <<= 1) {
        int v = __shfl_up(s, off);
        if (lane >= off) s += v;
    }
    __shared__ int wtot[4];
    if (lane == 63) wtot[wave] = s;
    __syncthreads();
    int woff = 0;
#pragma unroll
    for (int i = 0; i < 4; ++i) woff += (i < wave) ? wtot[i] : 0;
    int excl = woff + s - tsum;         // exclusive prefix within block
    int l0 = excl;
    int l1 = l0 + d.x;
    int l2 = l1 + d.y;
    int l3 = l2 + d.z;
    if (base + 3 < n_nodes) {
        *(int4*)&local[base] = make_int4(l0, l1, l2, l3);
    } else {
        if (base + 0 < n_nodes) local[base + 0] = l0;
        if (base + 1 < n_nodes) local[base + 1] = l1;
        if (base + 2 < n_nodes) local[base + 2] = l2;
        if (base + 3 < n_nodes) local[base + 3] = l3;
    }
    if (threadIdx.x == 255) bsum[blockIdx.x] = excl + tsum;  // block total
}

// ---------------- B2: scan the (<=1024) block totals -------------------------
__global__ __launch_bounds__(1024) void k_scan_bsum(
    const int* __restrict__ bsum, int* __restrict__ boff,
    int* __restrict__ rowstart, int nb, int n_nodes, int n_edges)
{
    __shared__ int lds[1024];
    int t = threadIdx.x;
    lds[t] = (t < nb) ? bsum[t] : 0;
    __syncthreads();
    for (int off = 1; off < 1024; off <<= 1) {
        int v = (t >= off) ? lds[t - off] : 0;
        __syncthreads();
        lds[t] += v;
        __syncthreads();
    }
    if (t < nb) boff[t] = (t == 0) ? 0 : lds[t - 1];
    if (t == 0) rowstart[n_nodes] = n_edges;
}

// ---------------- B3: apply block offsets -> rowstart, cursor ----------------
__global__ __launch_bounds__(256) void k_scan_apply(
    const int* __restrict__ local, const int* __restrict__ boff,
    int* __restrict__ rowstart, int* __restrict__ cursor, int n_nodes)
{
    int base = blockIdx.x * 1024 + threadIdx.x * 4;
    int off = boff[blockIdx.x];
    if (base + 3 < n_nodes) {
        int4 l = *(const int4*)&local[base];
        int4 r = make_int4(l.x + off, l.y + off, l.z + off, l.w + off);
        *(int4*)&rowstart[base] = r;
        *(int4*)&cursor[base] = r;
    } else {
        for (int i = 0; i < 4; ++i) {
            if (base + i < n_nodes) {
                int r = local[base + i] + off;
                rowstart[base + i] = r;
                cursor[base + i] = r;
            }
        }
    }
}

// ---------------- C: CSR fill, XCD-grouped to keep writes L2-resident --------
// Each group (blockIdx&7 -> same XCD under round-robin dispatch) handles one
// 1/8th node range; its eidx slice (~800KB) stays in that XCD's 4MB L2, so
// scattered 4B stores accumulate full lines instead of writing through.
// Rescans the edge list per group: +102MB coalesced reads, -95MB HBM writes.
__global__ __launch_bounds__(256) void k_fill(
    const int* __restrict__ src, const int* __restrict__ dst,
    int* __restrict__ cursor, int* __restrict__ eidx, int n_edges, int n_nodes)
{
    int grp = blockIdx.x & (FILL_GRP - 1);
    int lo = (int)((long long)grp * n_nodes / FILL_GRP);
    int hi = (int)((long long)(grp + 1) * n_nodes / FILL_GRP);
    int nblk = gridDim.x >> 3;
    int bid = blockIdx.x >> 3;
    for (int e = bid * 256 + threadIdx.x; e < n_edges; e += nblk * 256) {
        int v = dst[e];
        if (v >= lo && v < hi) {
            int pos = atomicAdd(&cursor[v], 1);
            eidx[pos] = src[e];
        }
    }
}

// ---------------- D: layer-1 gather: hn = (sum feat[src] + feat[v])/(deg+1) --
__global__ __launch_bounds__(256) void k_agg1(
    const int* __restrict__ rowstart, const int* __restrict__ eidx,
    const float* __restrict__ feat0, float* __restrict__ hn, int n_nodes)
{
    int w = (int)((blockIdx.x * 256u + threadIdx.x) >> 6);
    int lane = threadIdx.x & 63;
    if (w >= n_nodes) return;
    int v = w;
    int e0 = rowstart[v], e1 = rowstart[v + 1];
    int nedge = e1 - e0;
    int sub = lane >> 5;          // half-wave: 0 = even edges, 1 = odd edges
    int d = lane & 31;
    bool act = d < IN_DIM;
    float acc = 0.f;
    for (int base = 0; base < nedge; base += 64) {
        int cnt = min(64, nedge - base);
        int idx = 0;
        if (lane < cnt) idx = eidx[e0 + base + lane];
        int j = 0;
        for (; j + 8 <= cnt; j += 8) {
            int a0 = __builtin_amdgcn_readlane(idx, j);
            int a1 = __builtin_amdgcn_readlane(idx, j + 1);
            int b0 = __builtin_amdgcn_readlane(idx, j + 2);
            int b1 = __builtin_amdgcn_readlane(idx, j + 3);
            int c0 = __builtin_amdgcn_readlane(idx, j + 4);
            int c1 = __builtin_amdgcn_readlane(idx, j + 5);
            int d0 = __builtin_amdgcn_readlane(idx, j + 6);
            int d1 = __builtin_amdgcn_readlane(idx, j + 7);
            int s0 = sub ? a1 : a0;
            int s1 = sub ? b1 : b0;
            int s2 = sub ? c1 : c0;
            int s3 = sub ? d1 : d0;
            if (act) {
                float f0 = feat0[(size_t)s0 * IN_DIM + d];
                float f1 = feat0[(size_t)s1 * IN_DIM + d];
                float f2 = feat0[(size_t)s2 * IN_DIM + d];
                float f3 = feat0[(size_t)s3 * IN_DIM + d];
                acc += f0 + f1 + f2 + f3;
            }
        }
        for (; j < cnt; j += 2) {
            int a0 = __builtin_amdgcn_readlane(idx, j);
            int a1 = __builtin_amdgcn_readlane(idx, min(j + 1, cnt - 1));
            int s = sub ? a1 : a0;
            if (act && (j + sub < cnt)) acc += feat0[(size_t)s * IN_DIM + d];
        }
    }
    acc += __shfl_xor(acc, 32);   // combine even/odd half-wave partials
    if (lane < IN_DIM) {
        hn[(size_t)v * IN_DIM + lane] =
            (acc + feat0[(size_t)v * IN_DIM + lane]) / ((float)nedge + 1.0f);
    }
}

// ---------------- E: node transform: m1 = relu(hn@W1+b1)/||.|| @ W2 ----------
__global__ __launch_bounds__(256) void k_node(
    const float* __restrict__ hn, const float* __restrict__ W1,
    const float* __restrict__ b1, const float* __restrict__ W2,
    float* __restrict__ m1, int n_nodes)
{
    __shared__ float sW1[IN_DIM * HID];
    __shared__ float sb1[HID];
    __shared__ float sW2[HID * OUTD];
    __shared__ float sh1[4][2][HID];
    __shared__ float shn[4][2][IN_DIM + 1];

    for (int i = threadIdx.x; i < IN_DIM * HID; i += 256) sW1[i] = W1[i];
    if (threadIdx.x < HID) sb1[threadIdx.x] = b1[threadIdx.x];
    for (int i = threadIdx.x; i < HID * OUTD; i += 256) sW2[i] = W2[i];
    __syncthreads();   // the only barrier: weight staging is cross-wave

    int wave = threadIdx.x >> 6;
    int lane = threadIdx.x & 63;

    for (int vb = blockIdx.x * 8; vb < n_nodes; vb += gridDim.x * 8) {
        int vbase = vb + wave * 2;

        if (lane < 2 * IN_DIM) {
            int tn = lane / IN_DIM, d = lane % IN_DIM;
            int v = vbase + tn;
            if (v < n_nodes) shn[wave][tn][d] = hn[(size_t)v * IN_DIM + d];
        }
        // intra-wave LDS RAW: lockstep + compiler lgkmcnt, no barrier

        int k0 = lane * 2;
        float sA0 = sb1[k0], sA1 = sb1[k0 + 1];
        float sB0 = sA0, sB1 = sA1;
#pragma unroll
        for (int d = 0; d < IN_DIM; ++d) {
            float2 wv = *(const float2*)&sW1[d * HID + k0];
            float a = shn[wave][0][d];
            float b = shn[wave][1][d];
            sA0 += a * wv.x; sA1 += a * wv.y;
            sB0 += b * wv.x; sB1 += b * wv.y;
        }
        sA0 = fmaxf(sA0, 0.f); sA1 = fmaxf(sA1, 0.f);
        sB0 = fmaxf(sB0, 0.f); sB1 = fmaxf(sB1, 0.f);
        float ssqA = sA0 * sA0 + sA1 * sA1;
        float ssqB = sB0 * sB0 + sB1 * sB1;
#pragma unroll
        for (int off = 32; off; off >>= 1) {
            ssqA += __shfl_xor(ssqA, off);
            ssqB += __shfl_xor(ssqB, off);
        }
        float scA = 1.0f / fmaxf(sqrtf(ssqA), 1e-12f);
        float scB = 1.0f / fmaxf(sqrtf(ssqB), 1e-12f);
        sh1[wave][0][k0] = sA0 * scA; sh1[wave][0][k0 + 1] = sA1 * scA;
        sh1[wave][1][k0] = sB0 * scB; sh1[wave][1][k0 + 1] = sB1 * scB;

        float acc0 = 0.f, acc1 = 0.f;
#pragma unroll 8
        for (int k = 0; k < HID; ++k) {
            float w2 = sW2[k * OUTD + lane];
            acc0 += sh1[wave][0][k] * w2;
            acc1 += sh1[wave][1][k] * w2;
        }
        int v0 = vbase, v1 = vbase + 1;
        if (v0 < n_nodes) m1[(size_t)v0 * OUTD + lane] = acc0;
        if (v1 < n_nodes) m1[(size_t)v1 * OUTD + lane] = acc1;
    }
}

// ---------------- F: layer-2 gather fused with per-graph mean ----------------
__global__ __launch_bounds__(256) void k_agg2g(
    const int* __restrict__ rowstart, const int* __restrict__ eidx,
    const float* __restrict__ m1, const int* __restrict__ gids,
    float* __restrict__ gpart, float* __restrict__ gcnt, int n_nodes)
{
    __shared__ float lsum[NGR * OUTD];
    __shared__ float lcnt[NGR];
    for (int i = threadIdx.x; i < NGR * OUTD; i += 256) lsum[i] = 0.f;
    if (threadIdx.x < NGR) lcnt[threadIdx.x] = 0.f;
    __syncthreads();

    int lane = threadIdx.x & 63;
    int w = (int)((blockIdx.x * 256u + threadIdx.x) >> 6);
    int nw = (int)((gridDim.x * 256u) >> 6);
    for (int v = w; v < n_nodes; v += nw) {
        int e0 = rowstart[v], e1 = rowstart[v + 1];
        int nedge = e1 - e0;
        float acc = m1[(size_t)v * OUTD + lane];
        for (int base = 0; base < nedge; base += 64) {
            int cnt = min(64, nedge - base);
            int idx = 0;
            if (lane < cnt) idx = eidx[e0 + base + lane];
            int j = 0;
            for (; j + 4 <= cnt; j += 4) {
                int s0 = __builtin_amdgcn_readlane(idx, j);
                int s1 = __builtin_amdgcn_readlane(idx, j + 1);
                int s2 = __builtin_amdgcn_readlane(idx, j + 2);
                int s3 = __builtin_amdgcn_readlane(idx, j + 3);
                float a0 = m1[(size_t)s0 * OUTD + lane];
                float a1 = m1[(size_t)s1 * OUTD + lane];
                float a2 = m1[(size_t)s2 * OUTD + lane];
                float a3 = m1[(size_t)s3 * OUTD + lane];
                acc += a0 + a1 + a2 + a3;
            }
            for (; j < cnt; ++j) {
                int s = __builtin_amdgcn_readlane(idx, j);
                acc += m1[(size_t)s * OUTD + lane];
            }
        }
        float inv = 1.0f / ((float)nedge + 1.0f);
        int g = gids[v];
        atomicAdd(&lsum[g * OUTD + lane], acc * inv);
        if (lane == 0) atomicAdd(&lcnt[g], 1.0f);
    }
    __syncthreads();
    float* gp = gpart + (size_t)(blockIdx.x & (NPART - 1)) * NGR * OUTD;
    for (int i = threadIdx.x; i < NGR * OUTD; i += 256) atomicAdd(&gp[i], lsum[i]);
    if (threadIdx.x < NGR) atomicAdd(&gcnt[threadIdx.x], lcnt[threadIdx.x]);
}

// ---------------- G: finalize: reduce partials, mean + b2 --------------------
__global__ __launch_bounds__(256) void k_final(
    const float* __restrict__ gpart, const float* __restrict__ gcnt,
    const float* __restrict__ b2, float* __restrict__ out)
{
    int i = blockIdx.x * 256 + threadIdx.x;
    if (i >= NGR * OUTD) return;
    int g = i >> 6, d = i & 63;
    float s = 0.f;
#pragma unroll
    for (int p = 0; p < NPART; ++p) s += gpart[(size_t)p * NGR * OUTD + i];
    float c = gcnt[g];
    out[i] = (c > 0.f) ? (s / c + b2[d]) : 0.f;
}

extern "C" void kernel_launch(void* const* d_in, const int* in_sizes, int n_in,
                              void* d_out, int out_size, void* d_ws, size_t ws_size,
                              hipStream_t stream) {
    const float* feat0 = (const float*)d_in[0];
    const float* W1    = (const float*)d_in[1];
    const float* b1    = (const float*)d_in[2];
    const float* W2    = (const float*)d_in[3];
    const float* b2    = (const float*)d_in[4];
    const int*   src   = (const int*)d_in[5];
    const int*   dst   = (const int*)d_in[6];
    const int*   gids  = (const int*)d_in[7];
    int n_edges = in_sizes[5];
    int n_nodes = in_sizes[7];

    int nb = (n_nodes + 1023) / 1024;   // scan blocks (98 for 100K nodes)

    // workspace layout (4B units): [zeroed: degi | gpart | gcnt] | rowstart |
    //                              cursor | local | bsum | boff | eidx | hn | m1
    int*   degi     = (int*)d_ws;
    float* gpart    = (float*)(degi + n_nodes);
    float* gcnt     = gpart + (size_t)NPART * NGR * OUTD;
    int*   rowstart = (int*)(gcnt + NGR);
    int*   cursor   = rowstart + n_nodes + 1;
    int*   local    = cursor + n_nodes;
    int*   bsum     = local + n_nodes;
    int*   boff     = bsum + nb;
    int*   eidx     = boff + nb;
    float* hn       = (float*)(eidx + n_edges);
    float* m1       = hn + (size_t)n_nodes * IN_DIM;

    size_t zero_units = (size_t)n_nodes + (size_t)NPART * NGR * OUTD + NGR;
    hipMemsetAsync(degi, 0, zero_units * 4, stream);

    unsigned blkE = (unsigned)((n_edges + 255) / 256);
    k_hist<<<blkE, 256, 0, stream>>>(dst, degi, n_edges);

    k_scan_local<<<nb, 256, 0, stream>>>(degi, local, bsum, n_nodes);
    k_scan_bsum<<<1, 1024, 0, stream>>>(bsum, boff, rowstart, nb, n_nodes, n_edges);
    k_scan_apply<<<nb, 256, 0, stream>>>(local, boff, rowstart, cursor, n_nodes);

    k_fill<<<2048, 256, 0, stream>>>(src, dst, cursor, eidx, n_edges, n_nodes);

    unsigned blkA = (unsigned)(((long long)n_nodes * 64 + 255) / 256);
    k_agg1<<<blkA, 256, 0, stream>>>(rowstart, eidx, feat0, hn, n_nodes);

    k_node<<<1024, 256, 0, stream>>>(hn, W1, b1, W2, m1, n_nodes);

    k_agg2g<<<2048, 256, 0, stream>>>(rowstart, eidx, m1, gids, gpart, gcnt, n_nodes);

    k_final<<<(NGR * OUTD + 255) / 256, 256, 0, stream>>>(gpart, gcnt, b2, (float*)d_out);
}

// Round 6
// 460.055 us; speedup vs baseline: 2.0559x; 1.0418x over previous
//
#include <hip/hip_runtime.h>

#define IN_DIM 23
#define HID 128
#define OUTD 64
#define NGR 64
#define NPART 32
#define FILL_GRP 8
#define FB_DIM 32   // feat padded to 32 bf16 = 64B aligned rows (1 line/edge)

static __device__ __forceinline__ unsigned short f2bf(float x) {
    unsigned u = __float_as_uint(x);
    unsigned r = (u + 0x7FFFu + ((u >> 16) & 1u)) >> 16;   // RNE
    return (unsigned short)r;
}
static __device__ __forceinline__ float bf2f(unsigned short u) {
    return __uint_as_float((unsigned)u << 16);             // exact
}

// ---------------- A: int degree histogram ------------------------------------
__global__ __launch_bounds__(256) void k_hist(
    const int* __restrict__ dst, int* __restrict__ degi, int n_edges)
{
    int e = blockIdx.x * 256 + threadIdx.x;
    if (e < n_edges) atomicAdd(&degi[dst[e]], 1);
}

// ---------------- A2: transcode feat0 -> bf16 padded rows --------------------
__global__ __launch_bounds__(256) void k_featb(
    const float* __restrict__ feat0, unsigned short* __restrict__ featb,
    int n_nodes)
{
    int i = blockIdx.x * 256 + threadIdx.x;
    if (i >= n_nodes * FB_DIM) return;
    int v = i >> 5, d = i & (FB_DIM - 1);
    float x = (d < IN_DIM) ? feat0[(size_t)v * IN_DIM + d] : 0.f;
    featb[i] = f2bf(x);
}

// ---------------- B1: per-block local exclusive scan + block totals ----------
__global__ __launch_bounds__(256) void k_scan_local(
    const int* __restrict__ degi, int* __restrict__ local,
    int* __restrict__ bsum, int n_nodes)
{
    int base = blockIdx.x * 1024 + threadIdx.x * 4;
    int4 d = {0, 0, 0, 0};
    if (base + 3 < n_nodes) {
        d = *(const int4*)&degi[base];
    } else {
        if (base + 0 < n_nodes) d.x = degi[base + 0];
        if (base + 1 < n_nodes) d.y = degi[base + 1];
        if (base + 2 < n_nodes) d.z = degi[base + 2];
        if (base + 3 < n_nodes) d.w = degi[base + 3];
    }
    int tsum = d.x + d.y + d.z + d.w;
    int lane = threadIdx.x & 63;
    int wave = threadIdx.x >> 6;
    int s = tsum;
#pragma unroll
    for (int off = 1; off < 64; off <<= 1) {
        int v = __shfl_up(s, off);
        if (lane >= off) s += v;
    }
    __shared__ int wtot[4];
    if (lane == 63) wtot[wave] = s;
    __syncthreads();
    int woff = 0;
#pragma unroll
    for (int i = 0; i < 4; ++i) woff += (i < wave) ? wtot[i] : 0;
    int excl = woff + s - tsum;
    int l0 = excl;
    int l1 = l0 + d.x;
    int l2 = l1 + d.y;
    int l3 = l2 + d.z;
    if (base + 3 < n_nodes) {
        *(int4*)&local[base] = make_int4(l0, l1, l2, l3);
    } else {
        if (base + 0 < n_nodes) local[base + 0] = l0;
        if (base + 1 < n_nodes) local[base + 1] = l1;
        if (base + 2 < n_nodes) local[base + 2] = l2;
        if (base + 3 < n_nodes) local[base + 3] = l3;
    }
    if (threadIdx.x == 255) bsum[blockIdx.x] = excl + tsum;
}

// ---------------- B2: scan the (<=1024) block totals -------------------------
__global__ __launch_bounds__(1024) void k_scan_bsum(
    const int* __restrict__ bsum, int* __restrict__ boff,
    int* __restrict__ rowstart, int nb, int n_nodes, int n_edges)
{
    __shared__ int lds[1024];
    int t = threadIdx.x;
    lds[t] = (t < nb) ? bsum[t] : 0;
    __syncthreads();
    for (int off = 1; off < 1024; off <<= 1) {
        int v = (t >= off) ? lds[t - off] : 0;
        __syncthreads();
        lds[t] += v;
        __syncthreads();
    }
    if (t < nb) boff[t] = (t == 0) ? 0 : lds[t - 1];
    if (t == 0) rowstart[n_nodes] = n_edges;
}

// ---------------- B3: apply block offsets -> rowstart, cursor ----------------
__global__ __launch_bounds__(256) void k_scan_apply(
    const int* __restrict__ local, const int* __restrict__ boff,
    int* __restrict__ rowstart, int* __restrict__ cursor, int n_nodes)
{
    int base = blockIdx.x * 1024 + threadIdx.x * 4;
    int off = boff[blockIdx.x];
    if (base + 3 < n_nodes) {
        int4 l = *(const int4*)&local[base];
        int4 r = make_int4(l.x + off, l.y + off, l.z + off, l.w + off);
        *(int4*)&rowstart[base] = r;
        *(int4*)&cursor[base] = r;
    } else {
        for (int i = 0; i < 4; ++i) {
            if (base + i < n_nodes) {
                int r = local[base + i] + off;
                rowstart[base + i] = r;
                cursor[base + i] = r;
            }
        }
    }
}

// ---------------- C: CSR fill, XCD-grouped to keep writes L2-resident --------
__global__ __launch_bounds__(256) void k_fill(
    const int* __restrict__ src, const int* __restrict__ dst,
    int* __restrict__ cursor, int* __restrict__ eidx, int n_edges, int n_nodes)
{
    int grp = blockIdx.x & (FILL_GRP - 1);
    int lo = (int)((long long)grp * n_nodes / FILL_GRP);
    int hi = (int)((long long)(grp + 1) * n_nodes / FILL_GRP);
    int nblk = gridDim.x >> 3;
    int bid = blockIdx.x >> 3;
    for (int e = bid * 256 + threadIdx.x; e < n_edges; e += nblk * 256) {
        int v = dst[e];
        if (v >= lo && v < hi) {
            int pos = atomicAdd(&cursor[v], 1);
            eidx[pos] = src[e];
        }
    }
}

// ---------------- D: layer-1 gather on bf16 padded rows (1 line/edge) --------
__global__ __launch_bounds__(256) void k_agg1(
    const int* __restrict__ rowstart, const int* __restrict__ eidx,
    const unsigned short* __restrict__ featb, const float* __restrict__ feat0,
    float* __restrict__ hn, int n_nodes)
{
    int w = (int)((blockIdx.x * 256u + threadIdx.x) >> 6);
    int lane = threadIdx.x & 63;
    if (w >= n_nodes) return;
    int v = w;
    int e0 = rowstart[v], e1 = rowstart[v + 1];
    int nedge = e1 - e0;
    int sub = lane >> 5;          // half-wave: 0 = even edges, 1 = odd edges
    int d = lane & 31;            // padded dims: d>=IN_DIM reads zeros
    float acc = 0.f;
    for (int base = 0; base < nedge; base += 64) {
        int cnt = min(64, nedge - base);
        int idx = 0;
        if (lane < cnt) idx = eidx[e0 + base + lane];
        int j = 0;
        for (; j + 8 <= cnt; j += 8) {
            int a0 = __builtin_amdgcn_readlane(idx, j);
            int a1 = __builtin_amdgcn_readlane(idx, j + 1);
            int b0 = __builtin_amdgcn_readlane(idx, j + 2);
            int b1 = __builtin_amdgcn_readlane(idx, j + 3);
            int c0 = __builtin_amdgcn_readlane(idx, j + 4);
            int c1 = __builtin_amdgcn_readlane(idx, j + 5);
            int d0 = __builtin_amdgcn_readlane(idx, j + 6);
            int d1 = __builtin_amdgcn_readlane(idx, j + 7);
            int s0 = sub ? a1 : a0;
            int s1 = sub ? b1 : b0;
            int s2 = sub ? c1 : c0;
            int s3 = sub ? d1 : d0;
            unsigned short u0 = featb[(size_t)s0 * FB_DIM + d];
            unsigned short u1 = featb[(size_t)s1 * FB_DIM + d];
            unsigned short u2 = featb[(size_t)s2 * FB_DIM + d];
            unsigned short u3 = featb[(size_t)s3 * FB_DIM + d];
            acc += bf2f(u0) + bf2f(u1) + bf2f(u2) + bf2f(u3);
        }
        for (; j < cnt; j += 2) {
            int a0 = __builtin_amdgcn_readlane(idx, j);
            int a1 = __builtin_amdgcn_readlane(idx, min(j + 1, cnt - 1));
            int s = sub ? a1 : a0;
            if (j + sub < cnt) acc += bf2f(featb[(size_t)s * FB_DIM + d]);
        }
    }
    acc += __shfl_xor(acc, 32);   // combine even/odd half-wave partials
    if (lane < IN_DIM) {
        hn[(size_t)v * IN_DIM + lane] =
            (acc + feat0[(size_t)v * IN_DIM + lane]) / ((float)nedge + 1.0f);
    }
}

// ---------------- E: node transform -> m1 stored bf16 ------------------------
__global__ __launch_bounds__(256) void k_node(
    const float* __restrict__ hn, const float* __restrict__ W1,
    const float* __restrict__ b1, const float* __restrict__ W2,
    unsigned short* __restrict__ m1, int n_nodes)
{
    __shared__ float sW1[IN_DIM * HID];
    __shared__ float sb1[HID];
    __shared__ float sW2[HID * OUTD];
    __shared__ float sh1[4][2][HID];
    __shared__ float shn[4][2][IN_DIM + 1];

    for (int i = threadIdx.x; i < IN_DIM * HID; i += 256) sW1[i] = W1[i];
    if (threadIdx.x < HID) sb1[threadIdx.x] = b1[threadIdx.x];
    for (int i = threadIdx.x; i < HID * OUTD; i += 256) sW2[i] = W2[i];
    __syncthreads();   // the only barrier: weight staging is cross-wave

    int wave = threadIdx.x >> 6;
    int lane = threadIdx.x & 63;

    for (int vb = blockIdx.x * 8; vb < n_nodes; vb += gridDim.x * 8) {
        int vbase = vb + wave * 2;

        if (lane < 2 * IN_DIM) {
            int tn = lane / IN_DIM, d = lane % IN_DIM;
            int v = vbase + tn;
            if (v < n_nodes) shn[wave][tn][d] = hn[(size_t)v * IN_DIM + d];
        }
        // intra-wave LDS RAW: lockstep + compiler lgkmcnt, no barrier

        int k0 = lane * 2;
        float sA0 = sb1[k0], sA1 = sb1[k0 + 1];
        float sB0 = sA0, sB1 = sA1;
#pragma unroll
        for (int d = 0; d < IN_DIM; ++d) {
            float2 wv = *(const float2*)&sW1[d * HID + k0];
            float a = shn[wave][0][d];
            float b = shn[wave][1][d];
            sA0 += a * wv.x; sA1 += a * wv.y;
            sB0 += b * wv.x; sB1 += b * wv.y;
        }
        sA0 = fmaxf(sA0, 0.f); sA1 = fmaxf(sA1, 0.f);
        sB0 = fmaxf(sB0, 0.f); sB1 = fmaxf(sB1, 0.f);
        float ssqA = sA0 * sA0 + sA1 * sA1;
        float ssqB = sB0 * sB0 + sB1 * sB1;
#pragma unroll
        for (int off = 32; off; off >>= 1) {
            ssqA += __shfl_xor(ssqA, off);
            ssqB += __shfl_xor(ssqB, off);
        }
        float scA = 1.0f / fmaxf(sqrtf(ssqA), 1e-12f);
        float scB = 1.0f / fmaxf(sqrtf(ssqB), 1e-12f);
        sh1[wave][0][k0] = sA0 * scA; sh1[wave][0][k0 + 1] = sA1 * scA;
        sh1[wave][1][k0] = sB0 * scB; sh1[wave][1][k0 + 1] = sB1 * scB;

        float acc0 = 0.f, acc1 = 0.f;
#pragma unroll 8
        for (int k = 0; k < HID; ++k) {
            float w2 = sW2[k * OUTD + lane];
            acc0 += sh1[wave][0][k] * w2;
            acc1 += sh1[wave][1][k] * w2;
        }
        int v0 = vbase, v1 = vbase + 1;
        if (v0 < n_nodes) m1[(size_t)v0 * OUTD + lane] = f2bf(acc0);
        if (v1 < n_nodes) m1[(size_t)v1 * OUTD + lane] = f2bf(acc1);
    }
}

// ---------------- F: layer-2 gather (bf16 m1, 2 lines/edge) + graph mean -----
__global__ __launch_bounds__(256) void k_agg2g(
    const int* __restrict__ rowstart, const int* __restrict__ eidx,
    const unsigned short* __restrict__ m1, const int* __restrict__ gids,
    float* __restrict__ gpart, float* __restrict__ gcnt, int n_nodes)
{
    __shared__ float lsum[NGR * OUTD];
    __shared__ float lcnt[NGR];
    for (int i = threadIdx.x; i < NGR * OUTD; i += 256) lsum[i] = 0.f;
    if (threadIdx.x < NGR) lcnt[threadIdx.x] = 0.f;
    __syncthreads();

    int lane = threadIdx.x & 63;
    int w = (int)((blockIdx.x * 256u + threadIdx.x) >> 6);
    int nw = (int)((gridDim.x * 256u) >> 6);
    for (int v = w; v < n_nodes; v += nw) {
        int e0 = rowstart[v], e1 = rowstart[v + 1];
        int nedge = e1 - e0;
        float acc = bf2f(m1[(size_t)v * OUTD + lane]);
        for (int base = 0; base < nedge; base += 64) {
            int cnt = min(64, nedge - base);
            int idx = 0;
            if (lane < cnt) idx = eidx[e0 + base + lane];
            int j = 0;
            for (; j + 8 <= cnt; j += 8) {
                int s0 = __builtin_amdgcn_readlane(idx, j);
                int s1 = __builtin_amdgcn_readlane(idx, j + 1);
                int s2 = __builtin_amdgcn_readlane(idx, j + 2);
                int s3 = __builtin_amdgcn_readlane(idx, j + 3);
                int s4 = __builtin_amdgcn_readlane(idx, j + 4);
                int s5 = __builtin_amdgcn_readlane(idx, j + 5);
                int s6 = __builtin_amdgcn_readlane(idx, j + 6);
                int s7 = __builtin_amdgcn_readlane(idx, j + 7);
                unsigned short u0 = m1[(size_t)s0 * OUTD + lane];
                unsigned short u1 = m1[(size_t)s1 * OUTD + lane];
                unsigned short u2 = m1[(size_t)s2 * OUTD + lane];
                unsigned short u3 = m1[(size_t)s3 * OUTD + lane];
                unsigned short u4 = m1[(size_t)s4 * OUTD + lane];
                unsigned short u5 = m1[(size_t)s5 * OUTD + lane];
                unsigned short u6 = m1[(size_t)s6 * OUTD + lane];
                unsigned short u7 = m1[(size_t)s7 * OUTD + lane];
                acc += bf2f(u0) + bf2f(u1) + bf2f(u2) + bf2f(u3)
                     + bf2f(u4) + bf2f(u5) + bf2f(u6) + bf2f(u7);
            }
            for (; j < cnt; ++j) {
                int s = __builtin_amdgcn_readlane(idx, j);
                acc += bf2f(m1[(size_t)s * OUTD + lane]);
            }
        }
        float inv = 1.0f / ((float)nedge + 1.0f);
        int g = gids[v];
        atomicAdd(&lsum[g * OUTD + lane], acc * inv);
        if (lane == 0) atomicAdd(&lcnt[g], 1.0f);
    }
    __syncthreads();
    float* gp = gpart + (size_t)(blockIdx.x & (NPART - 1)) * NGR * OUTD;
    for (int i = threadIdx.x; i < NGR * OUTD; i += 256) atomicAdd(&gp[i], lsum[i]);
    if (threadIdx.x < NGR) atomicAdd(&gcnt[threadIdx.x], lcnt[threadIdx.x]);
}

// ---------------- G: finalize: reduce partials, mean + b2 --------------------
__global__ __launch_bounds__(256) void k_final(
    const float* __restrict__ gpart, const float* __restrict__ gcnt,
    const float* __restrict__ b2, float* __restrict__ out)
{
    int i = blockIdx.x * 256 + threadIdx.x;
    if (i >= NGR * OUTD) return;
    int g = i >> 6, d = i & 63;
    float s = 0.f;
#pragma unroll
    for (int p = 0; p < NPART; ++p) s += gpart[(size_t)p * NGR * OUTD + i];
    float c = gcnt[g];
    out[i] = (c > 0.f) ? (s / c + b2[d]) : 0.f;
}

extern "C" void kernel_launch(void* const* d_in, const int* in_sizes, int n_in,
                              void* d_out, int out_size, void* d_ws, size_t ws_size,
                              hipStream_t stream) {
    const float* feat0 = (const float*)d_in[0];
    const float* W1    = (const float*)d_in[1];
    const float* b1    = (const float*)d_in[2];
    const float* W2    = (const float*)d_in[3];
    const float* b2    = (const float*)d_in[4];
    const int*   src   = (const int*)d_in[5];
    const int*   dst   = (const int*)d_in[6];
    const int*   gids  = (const int*)d_in[7];
    int n_edges = in_sizes[5];
    int n_nodes = in_sizes[7];

    int nb = (n_nodes + 1023) / 1024;   // scan blocks (98 for 100K nodes)

    // workspace layout (4B units): [zeroed: degi | gpart | gcnt] | rowstart |
    //                    cursor | local | bsum | boff | eidx | hn | m1b | featb
    int*   degi     = (int*)d_ws;
    float* gpart    = (float*)(degi + n_nodes);
    float* gcnt     = gpart + (size_t)NPART * NGR * OUTD;
    int*   rowstart = (int*)(gcnt + NGR);
    int*   cursor   = rowstart + n_nodes + 1;
    int*   local    = cursor + n_nodes;
    int*   bsum     = local + n_nodes;
    int*   boff     = bsum + nb;
    int*   eidx     = boff + nb;
    float* hn       = (float*)(eidx + n_edges);
    unsigned short* m1b   = (unsigned short*)(hn + (size_t)n_nodes * IN_DIM);
    unsigned short* featb = m1b + (size_t)n_nodes * OUTD;

    size_t zero_units = (size_t)n_nodes + (size_t)NPART * NGR * OUTD + NGR;
    hipMemsetAsync(degi, 0, zero_units * 4, stream);

    unsigned blkE = (unsigned)((n_edges + 255) / 256);
    k_hist<<<blkE, 256, 0, stream>>>(dst, degi, n_edges);

    k_featb<<<(unsigned)(((long long)n_nodes * FB_DIM + 255) / 256), 256, 0, stream>>>(
        feat0, featb, n_nodes);

    k_scan_local<<<nb, 256, 0, stream>>>(degi, local, bsum, n_nodes);
    k_scan_bsum<<<1, 1024, 0, stream>>>(bsum, boff, rowstart, nb, n_nodes, n_edges);
    k_scan_apply<<<nb, 256, 0, stream>>>(local, boff, rowstart, cursor, n_nodes);

    k_fill<<<2048, 256, 0, stream>>>(src, dst, cursor, eidx, n_edges, n_nodes);

    unsigned blkA = (unsigned)(((long long)n_nodes * 64 + 255) / 256);
    k_agg1<<<blkA, 256, 0, stream>>>(rowstart, eidx, featb, feat0, hn, n_nodes);

    k_node<<<1024, 256, 0, stream>>>(hn, W1, b1, W2, m1b, n_nodes);

    k_agg2g<<<2048, 256, 0, stream>>>(rowstart, eidx, m1b, gids, gpart, gcnt, n_nodes);

    k_final<<<(NGR * OUTD + 255) / 256, 256, 0, stream>>>(gpart, gcnt, b2, (float*)d_out);
}

// Round 7
// 384.815 us; speedup vs baseline: 2.4578x; 1.1955x over previous
//
#include <hip/hip_runtime.h>

#define IN_DIM 23
#define HID 128
#define OUTD 64
#define NGR 64
#define NPART 32
#define FILL_GRP 8
#define FB_DIM 32    // feat padded to 32 bf16 = 64B aligned rows (1 line/edge)
#define PH_STRIDE 136  // 16 rows x 136 bf16: 272B row stride (16B-aligned, bank-spread)

typedef __attribute__((ext_vector_type(8))) short bf16x8;
typedef __attribute__((ext_vector_type(4))) float f32x4;

static __device__ __forceinline__ unsigned short f2bf(float x) {
    unsigned u = __float_as_uint(x);
    unsigned r = (u + 0x7FFFu + ((u >> 16) & 1u)) >> 16;   // RNE
    return (unsigned short)r;
}
static __device__ __forceinline__ float bf2f(unsigned short u) {
    return __uint_as_float((unsigned)u << 16);             // exact
}

// ---------------- A: int degree histogram ------------------------------------
__global__ __launch_bounds__(256) void k_hist(
    const int* __restrict__ dst, int* __restrict__ degi, int n_edges)
{
    int e = blockIdx.x * 256 + threadIdx.x;
    if (e < n_edges) atomicAdd(&degi[dst[e]], 1);
}

// ---------------- A2: transcode feat0 -> bf16 padded rows --------------------
__global__ __launch_bounds__(256) void k_featb(
    const float* __restrict__ feat0, unsigned short* __restrict__ featb,
    int n_nodes)
{
    int i = blockIdx.x * 256 + threadIdx.x;
    if (i >= n_nodes * FB_DIM) return;
    int v = i >> 5, d = i & (FB_DIM - 1);
    float x = (d < IN_DIM) ? feat0[(size_t)v * IN_DIM + d] : 0.f;
    featb[i] = f2bf(x);
}

// ---------------- A3: weight transpose+pad to bf16 MFMA B-operand layout -----
// W1t[h][d] (128x32, d padded) and W2t[o][k] (64x128): B-frag = 8 consecutive
// k for fixed n -> one 16B load per fragment.
__global__ __launch_bounds__(256) void k_wprep(
    const float* __restrict__ W1, const float* __restrict__ W2,
    unsigned short* __restrict__ W1t, unsigned short* __restrict__ W2t)
{
    int i = blockIdx.x * 256 + threadIdx.x;
    if (i < HID * 32) {
        int h = i >> 5, d = i & 31;
        W1t[i] = f2bf((d < IN_DIM) ? W1[d * HID + h] : 0.f);
    } else if (i < HID * 32 + OUTD * HID) {
        int j = i - HID * 32;
        int o = j >> 7, k = j & 127;
        W2t[j] = f2bf(W2[k * OUTD + o]);
    }
}

// ---------------- B1: per-block local exclusive scan + block totals ----------
__global__ __launch_bounds__(256) void k_scan_local(
    const int* __restrict__ degi, int* __restrict__ local,
    int* __restrict__ bsum, int n_nodes)
{
    int base = blockIdx.x * 1024 + threadIdx.x * 4;
    int4 d = {0, 0, 0, 0};
    if (base + 3 < n_nodes) {
        d = *(const int4*)&degi[base];
    } else {
        if (base + 0 < n_nodes) d.x = degi[base + 0];
        if (base + 1 < n_nodes) d.y = degi[base + 1];
        if (base + 2 < n_nodes) d.z = degi[base + 2];
        if (base + 3 < n_nodes) d.w = degi[base + 3];
    }
    int tsum = d.x + d.y + d.z + d.w;
    int lane = threadIdx.x & 63;
    int wave = threadIdx.x >> 6;
    int s = tsum;
#pragma unroll
    for (int off = 1; off < 64; off <<= 1) {
        int v = __shfl_up(s, off);
        if (lane >= off) s += v;
    }
    __shared__ int wtot[4];
    if (lane == 63) wtot[wave] = s;
    __syncthreads();
    int woff = 0;
#pragma unroll
    for (int i = 0; i < 4; ++i) woff += (i < wave) ? wtot[i] : 0;
    int excl = woff + s - tsum;
    int l0 = excl;
    int l1 = l0 + d.x;
    int l2 = l1 + d.y;
    int l3 = l2 + d.z;
    if (base + 3 < n_nodes) {
        *(int4*)&local[base] = make_int4(l0, l1, l2, l3);
    } else {
        if (base + 0 < n_nodes) local[base + 0] = l0;
        if (base + 1 < n_nodes) local[base + 1] = l1;
        if (base + 2 < n_nodes) local[base + 2] = l2;
        if (base + 3 < n_nodes) local[base + 3] = l3;
    }
    if (threadIdx.x == 255) bsum[blockIdx.x] = excl + tsum;
}

// ---------------- B2: scan the (<=1024) block totals -------------------------
__global__ __launch_bounds__(1024) void k_scan_bsum(
    const int* __restrict__ bsum, int* __restrict__ boff,
    int* __restrict__ rowstart, int nb, int n_nodes, int n_edges)
{
    __shared__ int lds[1024];
    int t = threadIdx.x;
    lds[t] = (t < nb) ? bsum[t] : 0;
    __syncthreads();
    for (int off = 1; off < 1024; off <<= 1) {
        int v = (t >= off) ? lds[t - off] : 0;
        __syncthreads();
        lds[t] += v;
        __syncthreads();
    }
    if (t < nb) boff[t] = (t == 0) ? 0 : lds[t - 1];
    if (t == 0) rowstart[n_nodes] = n_edges;
}

// ---------------- B3: apply block offsets -> rowstart, cursor ----------------
__global__ __launch_bounds__(256) void k_scan_apply(
    const int* __restrict__ local, const int* __restrict__ boff,
    int* __restrict__ rowstart, int* __restrict__ cursor, int n_nodes)
{
    int base = blockIdx.x * 1024 + threadIdx.x * 4;
    int off = boff[blockIdx.x];
    if (base + 3 < n_nodes) {
        int4 l = *(const int4*)&local[base];
        int4 r = make_int4(l.x + off, l.y + off, l.z + off, l.w + off);
        *(int4*)&rowstart[base] = r;
        *(int4*)&cursor[base] = r;
    } else {
        for (int i = 0; i < 4; ++i) {
            if (base + i < n_nodes) {
                int r = local[base + i] + off;
                rowstart[base + i] = r;
                cursor[base + i] = r;
            }
        }
    }
}

// ---------------- C: CSR fill, XCD-grouped to keep writes L2-resident --------
__global__ __launch_bounds__(256) void k_fill(
    const int* __restrict__ src, const int* __restrict__ dst,
    int* __restrict__ cursor, int* __restrict__ eidx, int n_edges, int n_nodes)
{
    int grp = blockIdx.x & (FILL_GRP - 1);
    int lo = (int)((long long)grp * n_nodes / FILL_GRP);
    int hi = (int)((long long)(grp + 1) * n_nodes / FILL_GRP);
    int nblk = gridDim.x >> 3;
    int bid = blockIdx.x >> 3;
    for (int e = bid * 256 + threadIdx.x; e < n_edges; e += nblk * 256) {
        int v = dst[e];
        if (v >= lo && v < hi) {
            int pos = atomicAdd(&cursor[v], 1);
            eidx[pos] = src[e];
        }
    }
}

// ---------------- D: layer-1 gather -> hnb (bf16, padded 32) ----------------
// Output rows are directly MFMA-A-operand-ready (64B aligned).
__global__ __launch_bounds__(256) void k_agg1(
    const int* __restrict__ rowstart, const int* __restrict__ eidx,
    const unsigned short* __restrict__ featb, const float* __restrict__ feat0,
    unsigned short* __restrict__ hnb, int n_nodes)
{
    int w = (int)((blockIdx.x * 256u + threadIdx.x) >> 6);
    int lane = threadIdx.x & 63;
    if (w >= n_nodes) return;
    int v = w;
    int e0 = rowstart[v], e1 = rowstart[v + 1];
    int nedge = e1 - e0;
    int sub = lane >> 5;          // half-wave: 0 = even edges, 1 = odd edges
    int d = lane & 31;            // padded dims: d>=IN_DIM reads zeros
    float acc = 0.f;
    for (int base = 0; base < nedge; base += 64) {
        int cnt = min(64, nedge - base);
        int idx = 0;
        if (lane < cnt) idx = eidx[e0 + base + lane];
        int j = 0;
        for (; j + 8 <= cnt; j += 8) {
            int a0 = __builtin_amdgcn_readlane(idx, j);
            int a1 = __builtin_amdgcn_readlane(idx, j + 1);
            int b0 = __builtin_amdgcn_readlane(idx, j + 2);
            int b1 = __builtin_amdgcn_readlane(idx, j + 3);
            int c0 = __builtin_amdgcn_readlane(idx, j + 4);
            int c1 = __builtin_amdgcn_readlane(idx, j + 5);
            int d0 = __builtin_amdgcn_readlane(idx, j + 6);
            int d1 = __builtin_amdgcn_readlane(idx, j + 7);
            int s0 = sub ? a1 : a0;
            int s1 = sub ? b1 : b0;
            int s2 = sub ? c1 : c0;
            int s3 = sub ? d1 : d0;
            unsigned short u0 = featb[(size_t)s0 * FB_DIM + d];
            unsigned short u1 = featb[(size_t)s1 * FB_DIM + d];
            unsigned short u2 = featb[(size_t)s2 * FB_DIM + d];
            unsigned short u3 = featb[(size_t)s3 * FB_DIM + d];
            acc += bf2f(u0) + bf2f(u1) + bf2f(u2) + bf2f(u3);
        }
        for (; j < cnt; j += 2) {
            int a0 = __builtin_amdgcn_readlane(idx, j);
            int a1 = __builtin_amdgcn_readlane(idx, min(j + 1, cnt - 1));
            int s = sub ? a1 : a0;
            if (j + sub < cnt) acc += bf2f(featb[(size_t)s * FB_DIM + d]);
        }
    }
    acc += __shfl_xor(acc, 32);   // combine even/odd half-wave partials
    if (lane < FB_DIM) {
        float val = 0.f;
        if (lane < IN_DIM)
            val = (acc + feat0[(size_t)v * IN_DIM + lane]) / ((float)nedge + 1.0f);
        hnb[(size_t)v * FB_DIM + lane] = f2bf(val);
    }
}

// ---------------- E: MFMA node transform: m1 = relu(hn@W1+b1)/||.|| @ W2 -----
// One 16-node tile per wave via mfma_f32_16x16x32_bf16.
// A-layout: A[m=lane&15][k=quad*8+j]; B-layout: B[k=quad*8+j][n=lane&15];
// C/D: col=lane&15, row=quad*4+reg  [per cdna_hip_programming.md §3, m89/m120].
__global__ __launch_bounds__(256) void k_node(
    const unsigned short* __restrict__ hnb, const unsigned short* __restrict__ W1t,
    const float* __restrict__ b1, const unsigned short* __restrict__ W2t,
    unsigned short* __restrict__ m1, int n_nodes)
{
    __shared__ unsigned short ph[4][16 * PH_STRIDE];   // per-wave C->A transform
    int wave = threadIdx.x >> 6, lane = threadIdx.x & 63;
    int quad = lane >> 4, l15 = lane & 15;
    const f32x4 z4 = {0.f, 0.f, 0.f, 0.f};

    float bb[8];
#pragma unroll
    for (int t = 0; t < 8; ++t) bb[t] = b1[t * 16 + l15];

    for (int v0 = blockIdx.x * 64 + wave * 16; v0 < n_nodes; v0 += gridDim.x * 64) {
        // ---- layer 1: C1[16 nodes][128 hid] = hnb(16x32) @ W1(32x128)
        bf16x8 aH = {0, 0, 0, 0, 0, 0, 0, 0};
        int vA = v0 + l15;
        if (vA < n_nodes) aH = *(const bf16x8*)&hnb[(size_t)vA * FB_DIM + quad * 8];
        f32x4 c1[8];
#pragma unroll
        for (int t = 0; t < 8; ++t) {
            bf16x8 bw = *(const bf16x8*)&W1t[(t * 16 + l15) * 32 + quad * 8];
            c1[t] = __builtin_amdgcn_mfma_f32_16x16x32_bf16(aH, bw, z4, 0, 0, 0);
        }
        // ---- bias + relu + row L2-norm (rows m=quad*4+r live across 16 lanes)
        float ssq[4] = {0.f, 0.f, 0.f, 0.f};
#pragma unroll
        for (int t = 0; t < 8; ++t) {
#pragma unroll
            for (int r = 0; r < 4; ++r) {
                float x = fmaxf(c1[t][r] + bb[t], 0.f);
                c1[t][r] = x;
                ssq[r] += x * x;
            }
        }
#pragma unroll
        for (int off = 1; off < 16; off <<= 1) {
#pragma unroll
            for (int r = 0; r < 4; ++r) ssq[r] += __shfl_xor(ssq[r], off);
        }
        float inv[4];
#pragma unroll
        for (int r = 0; r < 4; ++r) inv[r] = 1.0f / fmaxf(sqrtf(ssq[r]), 1e-12f);
        // ---- C-layout -> A-layout via per-wave LDS round-trip (bf16)
#pragma unroll
        for (int t = 0; t < 8; ++t)
#pragma unroll
            for (int r = 0; r < 4; ++r)
                ph[wave][(quad * 4 + r) * PH_STRIDE + t * 16 + l15] =
                    f2bf(c1[t][r] * inv[r]);
        // ---- layer 2: C2[16 nodes][64 out] = P(16x128) @ W2(128x64)
        f32x4 c2[4] = {z4, z4, z4, z4};
#pragma unroll
        for (int ks = 0; ks < 4; ++ks) {
            bf16x8 aP = *(const bf16x8*)&ph[wave][l15 * PH_STRIDE + ks * 32 + quad * 8];
#pragma unroll
            for (int tn = 0; tn < 4; ++tn) {
                bf16x8 bw = *(const bf16x8*)&W2t[(tn * 16 + l15) * HID + ks * 32 + quad * 8];
                c2[tn] = __builtin_amdgcn_mfma_f32_16x16x32_bf16(aP, bw, c2[tn], 0, 0, 0);
            }
        }
#pragma unroll
        for (int tn = 0; tn < 4; ++tn)
#pragma unroll
            for (int r = 0; r < 4; ++r) {
                int v = v0 + quad * 4 + r;
                if (v < n_nodes) m1[(size_t)v * OUTD + tn * 16 + l15] = f2bf(c2[tn][r]);
            }
    }
}

// ---------------- F: layer-2 gather (bf16 m1) + per-graph mean ---------------
__global__ __launch_bounds__(256) void k_agg2g(
    const int* __restrict__ rowstart, const int* __restrict__ eidx,
    const unsigned short* __restrict__ m1, const int* __restrict__ gids,
    float* __restrict__ gpart, float* __restrict__ gcnt, int n_nodes)
{
    __shared__ float lsum[NGR * OUTD];
    __shared__ float lcnt[NGR];
    for (int i = threadIdx.x; i < NGR * OUTD; i += 256) lsum[i] = 0.f;
    if (threadIdx.x < NGR) lcnt[threadIdx.x] = 0.f;
    __syncthreads();

    int lane = threadIdx.x & 63;
    int w = (int)((blockIdx.x * 256u + threadIdx.x) >> 6);
    int nw = (int)((gridDim.x * 256u) >> 6);
    for (int v = w; v < n_nodes; v += nw) {
        int e0 = rowstart[v], e1 = rowstart[v + 1];
        int nedge = e1 - e0;
        float acc = bf2f(m1[(size_t)v * OUTD + lane]);
        for (int base = 0; base < nedge; base += 64) {
            int cnt = min(64, nedge - base);
            int idx = 0;
            if (lane < cnt) idx = eidx[e0 + base + lane];
            int j = 0;
            for (; j + 8 <= cnt; j += 8) {
                int s0 = __builtin_amdgcn_readlane(idx, j);
                int s1 = __builtin_amdgcn_readlane(idx, j + 1);
                int s2 = __builtin_amdgcn_readlane(idx, j + 2);
                int s3 = __builtin_amdgcn_readlane(idx, j + 3);
                int s4 = __builtin_amdgcn_readlane(idx, j + 4);
                int s5 = __builtin_amdgcn_readlane(idx, j + 5);
                int s6 = __builtin_amdgcn_readlane(idx, j + 6);
                int s7 = __builtin_amdgcn_readlane(idx, j + 7);
                unsigned short u0 = m1[(size_t)s0 * OUTD + lane];
                unsigned short u1 = m1[(size_t)s1 * OUTD + lane];
                unsigned short u2 = m1[(size_t)s2 * OUTD + lane];
                unsigned short u3 = m1[(size_t)s3 * OUTD + lane];
                unsigned short u4 = m1[(size_t)s4 * OUTD + lane];
                unsigned short u5 = m1[(size_t)s5 * OUTD + lane];
                unsigned short u6 = m1[(size_t)s6 * OUTD + lane];
                unsigned short u7 = m1[(size_t)s7 * OUTD + lane];
                acc += bf2f(u0) + bf2f(u1) + bf2f(u2) + bf2f(u3)
                     + bf2f(u4) + bf2f(u5) + bf2f(u6) + bf2f(u7);
            }
            for (; j < cnt; ++j) {
                int s = __builtin_amdgcn_readlane(idx, j);
                acc += bf2f(m1[(size_t)s * OUTD + lane]);
            }
        }
        float inv = 1.0f / ((float)nedge + 1.0f);
        int g = gids[v];
        atomicAdd(&lsum[g * OUTD + lane], acc * inv);
        if (lane == 0) atomicAdd(&lcnt[g], 1.0f);
    }
    __syncthreads();
    float* gp = gpart + (size_t)(blockIdx.x & (NPART - 1)) * NGR * OUTD;
    for (int i = threadIdx.x; i < NGR * OUTD; i += 256) atomicAdd(&gp[i], lsum[i]);
    if (threadIdx.x < NGR) atomicAdd(&gcnt[threadIdx.x], lcnt[threadIdx.x]);
}

// ---------------- G: finalize: reduce partials, mean + b2 --------------------
__global__ __launch_bounds__(256) void k_final(
    const float* __restrict__ gpart, const float* __restrict__ gcnt,
    const float* __restrict__ b2, float* __restrict__ out)
{
    int i = blockIdx.x * 256 + threadIdx.x;
    if (i >= NGR * OUTD) return;
    int g = i >> 6, d = i & 63;
    float s = 0.f;
#pragma unroll
    for (int p = 0; p < NPART; ++p) s += gpart[(size_t)p * NGR * OUTD + i];
    float c = gcnt[g];
    out[i] = (c > 0.f) ? (s / c + b2[d]) : 0.f;
}

extern "C" void kernel_launch(void* const* d_in, const int* in_sizes, int n_in,
                              void* d_out, int out_size, void* d_ws, size_t ws_size,
                              hipStream_t stream) {
    const float* feat0 = (const float*)d_in[0];
    const float* W1    = (const float*)d_in[1];
    const float* b1    = (const float*)d_in[2];
    const float* W2    = (const float*)d_in[3];
    const float* b2    = (const float*)d_in[4];
    const int*   src   = (const int*)d_in[5];
    const int*   dst   = (const int*)d_in[6];
    const int*   gids  = (const int*)d_in[7];
    int n_edges = in_sizes[5];
    int n_nodes = in_sizes[7];

    int nb = (n_nodes + 1023) / 1024;   // scan blocks (98 for 100K nodes)

    // workspace layout: 16B-aligned bf16 arrays first (W1t | W2t | hnb), then
    // 4B arrays: [zeroed: degi | gpart | gcnt] | rowstart | cursor | local |
    // bsum | boff | eidx | featb | m1b
    unsigned short* W1t = (unsigned short*)d_ws;
    unsigned short* W2t = W1t + HID * 32;
    unsigned short* hnb = W2t + (size_t)OUTD * HID;
    int*   degi     = (int*)(hnb + (size_t)n_nodes * FB_DIM);
    float* gpart    = (float*)(degi + n_nodes);
    float* gcnt     = gpart + (size_t)NPART * NGR * OUTD;
    int*   rowstart = (int*)(gcnt + NGR);
    int*   cursor   = rowstart + n_nodes + 1;
    int*   local    = cursor + n_nodes;
    int*   bsum     = local + n_nodes;
    int*   boff     = bsum + nb;
    int*   eidx     = boff + nb;
    unsigned short* featb = (unsigned short*)(eidx + n_edges);
    unsigned short* m1b   = featb + (size_t)n_nodes * FB_DIM;

    size_t zero_units = (size_t)n_nodes + (size_t)NPART * NGR * OUTD + NGR;
    hipMemsetAsync(degi, 0, zero_units * 4, stream);

    unsigned blkE = (unsigned)((n_edges + 255) / 256);
    k_hist<<<blkE, 256, 0, stream>>>(dst, degi, n_edges);

    k_featb<<<(unsigned)(((long long)n_nodes * FB_DIM + 255) / 256), 256, 0, stream>>>(
        feat0, featb, n_nodes);
    k_wprep<<<(HID * 32 + OUTD * HID + 255) / 256, 256, 0, stream>>>(W1, W2, W1t, W2t);

    k_scan_local<<<nb, 256, 0, stream>>>(degi, local, bsum, n_nodes);
    k_scan_bsum<<<1, 1024, 0, stream>>>(bsum, boff, rowstart, nb, n_nodes, n_edges);
    k_scan_apply<<<nb, 256, 0, stream>>>(local, boff, rowstart, cursor, n_nodes);

    k_fill<<<2048, 256, 0, stream>>>(src, dst, cursor, eidx, n_edges, n_nodes);

    unsigned blkA = (unsigned)(((long long)n_nodes * 64 + 255) / 256);
    k_agg1<<<blkA, 256, 0, stream>>>(rowstart, eidx, featb, feat0, hnb, n_nodes);

    k_node<<<1024, 256, 0, stream>>>(hnb, W1t, b1, W2t, m1b, n_nodes);

    k_agg2g<<<2048, 256, 0, stream>>>(rowstart, eidx, m1b, gids, gpart, gcnt, n_nodes);

    k_final<<<(NGR * OUTD + 255) / 256, 256, 0, stream>>>(gpart, gcnt, b2, (float*)d_out);
}